// Round 6
// baseline (155.695 us; speedup 1.0000x reference)
//
#include <hip/hip_runtime.h>
#include <math.h>

// S4 DPLR kernel + batched causal convolution via custom packed-real FFTs.
//
//  A) s4_khat_kernel : wave-per-l Cauchy sum (byte-identical, verified).
//  B) s4_tabs_kernel : LDS-staged Dirichlet odd bins + S_K + sigma-permuted
//       pair tables (heavy math byte-identical; only the sigma used for the
//       final table indices changed with the new factorization).
//  C) s4_conv_kernel v7 : RADIX-16 RESTRUCTURE. 8192 = 16*16*16*2:
//       fft_first_g16 (radix-16 from global, upper-half-zero specialized)
//       -> fft_mid16_f (size 512) -> fwd_tail32 (radix-16 size-32 + r2
//       merged, PAIR-SPLIT across threads with shfl_xor(1), const W32)
//       -> pointwise (same math, new sigma) -> inv_head32 -> fft_mid16_i
//       -> fft_last_g16 (writes y directly, lower half only).
//       7 passes / 6 barriers vs v4's 9/8; ~25% less LDS traffic; 2 twiddle
//       generations per direction instead of 3; 512 butterflies/stage = 1
//       per thread. v4 (50us) plateaued at the 9-pass schedule: VALUBusy
//       ~65-68%, occupancy 33/50 — barrier-drain bound. v6's b128 pairing
//       was a wash (LDS instrs halved but conflicts doubled).
//       Twiddles w^1..w^15 from TWO __sincosf (w1, w8) + 13 cmulf, depth<=4.
//       [Round 5 resubmit: round-4 bench died on container acquisition, no
//        verdict. Kernel re-audited (sigma re-derived, OOB, barrier
//        uniformity, pair-shfl reconvergence) and resubmitted byte-identical.]
//
// sigma for DIF radices (16,16,16,2):
//   k = e3*4096 + e2*256 + e1*16 + e0  ->  sig(k) = e0*512 + e1*32 + e2*2 + e3
// (sig(k) even <=> k < 4096; sig(4096) = 1 — same contract as the old sigma,
//  so the pointwise pair-loop and tabs structure are unchanged.)
//
// LDS addresses go through SW(x) = x ^ ((x>>4)&15) (v4's verified swizzle).
// Bank audit for the new strides (32 and 512 float2): each b64 access lands
// 4 lanes per 8B slot uniformly = the 512B/wave floor, conflict-free.

#define TPB 512

__device__ __forceinline__ int SW(int x){ return x ^ ((x >> 4) & 15); }

__device__ __forceinline__ float2 cadd(float2 a, float2 b){ return make_float2(a.x+b.x, a.y+b.y); }
__device__ __forceinline__ float2 csub(float2 a, float2 b){ return make_float2(a.x-b.x, a.y-b.y); }
__device__ __forceinline__ float2 cmulf(float2 a, float2 b){
  return make_float2(a.x*b.x - a.y*b.y, a.x*b.y + a.y*b.x);
}
__device__ __forceinline__ float2 cmulcf(float2 a, float2 b){  // a * conj(b)
  return make_float2(a.x*b.x + a.y*b.y, a.y*b.x - a.x*b.y);
}
template<int SGN>
__device__ __forceinline__ float2 muli(float2 v){
  return (SGN > 0) ? make_float2(-v.y, v.x) : make_float2(v.y, -v.x);
}

template<int SGN>   // -1: forward DFT8; +1: conj (unscaled inverse)
__device__ __forceinline__ void dft8(const float2* a, float2* X){
  const float C  = 0.70710678118654752f;
  const float SC = (SGN > 0) ? C : -C;
  float2 e0=cadd(a[0],a[4]), e1=csub(a[0],a[4]);
  float2 e2=cadd(a[2],a[6]), e3=csub(a[2],a[6]);
  float2 f0=cadd(a[1],a[5]), f1=csub(a[1],a[5]);
  float2 f2=cadd(a[3],a[7]), f3=csub(a[3],a[7]);
  float2 ie3 = muli<SGN>(e3), if3 = muli<SGN>(f3);
  float2 E0=cadd(e0,e2), E2=csub(e0,e2);
  float2 E1=cadd(e1,ie3), E3=csub(e1,ie3);
  float2 O0=cadd(f0,f2), O2=csub(f0,f2);
  float2 O1=cadd(f1,if3), O3=csub(f1,if3);
  float2 O2r = muli<SGN>(O2);
  float2 O1r = cmulf(O1, make_float2(C,  SC));
  float2 O3r = cmulf(O3, make_float2(-C, SC));
  X[0]=cadd(E0,O0);  X[4]=csub(E0,O0);
  X[1]=cadd(E1,O1r); X[5]=csub(E1,O1r);
  X[2]=cadd(E2,O2r); X[6]=csub(E2,O2r);
  X[3]=cadd(E3,O3r); X[7]=csub(E3,O3r);
}

// W16^q = e^{-2pi i q/16}, q=0..7 (forward sense)
__device__ __forceinline__ void w16_tab(float2* W){
  W[0] = make_float2( 1.f, 0.f);
  W[1] = make_float2( 0.923879533f, -0.382683432f);
  W[2] = make_float2( 0.707106781f, -0.707106781f);
  W[3] = make_float2( 0.382683432f, -0.923879533f);
  W[4] = make_float2( 0.f, -1.f);
  W[5] = make_float2(-0.382683432f, -0.923879533f);
  W[6] = make_float2(-0.707106781f, -0.707106781f);
  W[7] = make_float2(-0.923879533f, -0.382683432f);
}

// W32^q = e^{-2pi i q/32}, q=0..15 (forward sense)
__device__ __forceinline__ void w32_tab(float2* W){
  W[ 0] = make_float2( 1.f, 0.f);
  W[ 1] = make_float2( 0.980785280f, -0.195090322f);
  W[ 2] = make_float2( 0.923879533f, -0.382683432f);
  W[ 3] = make_float2( 0.831469612f, -0.555570233f);
  W[ 4] = make_float2( 0.707106781f, -0.707106781f);
  W[ 5] = make_float2( 0.555570233f, -0.831469612f);
  W[ 6] = make_float2( 0.382683432f, -0.923879533f);
  W[ 7] = make_float2( 0.195090322f, -0.980785280f);
  W[ 8] = make_float2( 0.f, -1.f);
  W[ 9] = make_float2(-0.195090322f, -0.980785280f);
  W[10] = make_float2(-0.382683432f, -0.923879533f);
  W[11] = make_float2(-0.555570233f, -0.831469612f);
  W[12] = make_float2(-0.707106781f, -0.707106781f);
  W[13] = make_float2(-0.831469612f, -0.555570233f);
  W[14] = make_float2(-0.923879533f, -0.382683432f);
  W[15] = make_float2(-0.980785280f, -0.195090322f);
}

// full 16-point DFT of a[0..15] (natural order), via even/odd dft8 split.
// SGN=-1 forward, +1 inverse (conj twiddles via cmulcf).
template<int SGN>
__device__ __forceinline__ void dft16(const float2* a, float2* X){
  float2 ae[8], ao[8], E[8], O[8];
#pragma unroll
  for (int q = 0; q < 8; q++){ ae[q] = a[2*q]; ao[q] = a[2*q+1]; }
  dft8<SGN>(ae, E);
  dft8<SGN>(ao, O);
  float2 W[8]; w16_tab(W);
#pragma unroll
  for (int q = 0; q < 8; q++){
    float2 t = (SGN < 0) ? cmulf(O[q], W[q]) : cmulcf(O[q], W[q]);
    X[q]     = cadd(E[q], t);
    X[q + 8] = csub(E[q], t);
  }
}

// W[q] = e^{i*ang*q}, q=1..15, from two sincosf (w1, w8); max depth 4.
__device__ __forceinline__ void wtree16(float ang, float2* W){
  float s1, c1, s8, c8;
  __sincosf(ang, &s1, &c1);
  __sincosf(8.f * ang, &s8, &c8);
  W[1] = make_float2(c1, s1);
  W[2] = cmulf(W[1], W[1]);
  W[3] = cmulf(W[2], W[1]);
  W[4] = cmulf(W[2], W[2]);
  W[5] = cmulf(W[4], W[1]);
  W[6] = cmulf(W[3], W[3]);
  W[7] = cmulf(W[4], W[3]);
  W[8] = make_float2(c8, s8);
#pragma unroll
  for (int r = 1; r < 8; r++) W[8 + r] = cmulf(W[8], W[r]);
}

// pass 1 fwd: size 8192, t=512. Butterfly u reads x[u+q*512] (q<8; q>=8 is
// the zero padding — never read). Coalesced global b64 loads. Writes LDS.
template<int T>
__device__ void fft_first_g16(float2* S, const float2* __restrict__ xb, int tid){
  const float ang = -6.283185307179586f / 8192.f;
  for (int u = tid; u < 512; u += T){
    float2 a[16], X[16];
#pragma unroll
    for (int q = 0; q < 8; q++)  a[q] = xb[u + q*512];
#pragma unroll
    for (int q = 8; q < 16; q++) a[q] = make_float2(0.f, 0.f);
    dft16<-1>(a, X);
    float2 W[16]; wtree16(ang * (float)u, W);
#pragma unroll
    for (int q = 1; q < 16; q++) X[q] = cmulf(X[q], W[q]);
#pragma unroll
    for (int q = 0; q < 16; q++) S[SW(u + q*512)] = X[q];
  }
}

// pass 2 fwd: size 512, t=32.
template<int T>
__device__ void fft_mid16_f(float2* S, int tid){
  const float ang = -6.283185307179586f / 512.f;
  for (int u = tid; u < 512; u += T){
    const int j = u & 31;
    const int base = ((u >> 5) << 9) + j;
    float2 a[16], X[16];
#pragma unroll
    for (int q = 0; q < 16; q++) a[q] = S[SW(base + (q << 5))];
    dft16<-1>(a, X);
    float2 W[16]; wtree16(ang * (float)j, W);
#pragma unroll
    for (int q = 1; q < 16; q++) X[q] = cmulf(X[q], W[q]);
#pragma unroll
    for (int q = 0; q < 16; q++) S[SW(base + (q << 5))] = X[q];
  }
}

// pass 3 fwd: merged size-32 radix-16 + size-2 r2, pair-split: thread pair
// (2v,2v+1) owns block [32v,32v+32); even thread does j=0 (even offsets),
// odd does j=1 (odd offsets, const W32 twiddles); r2 exchanged via shfl_xor.
// out[2q] = X0[q] + X1[q]*W32^q ; out[2q+1] = X0[q] - X1[q]*W32^q.
template<int T>
__device__ void fwd_tail32(float2* S, int tid){
  const int half = tid & 1;
  const float sg = half ? -1.f : 1.f;
  for (int v = tid >> 1; v < 256; v += (T >> 1)){
    const int base = v << 5;
    float2 a[16], X[16];
#pragma unroll
    for (int q = 0; q < 16; q++) a[q] = S[SW(base + 2*q + half)];
    dft16<-1>(a, X);
    if (half){
      float2 W[16]; w32_tab(W);
#pragma unroll
      for (int q = 1; q < 16; q++) X[q] = cmulf(X[q], W[q]);
    }
#pragma unroll
    for (int q = 0; q < 16; q++){
      float2 own = X[q], oth;
      oth.x = __shfl_xor(own.x, 1, 64);
      oth.y = __shfl_xor(own.y, 1, 64);
      S[SW(base + 2*q + half)] = make_float2(fmaf(sg, own.x, oth.x),
                                             fmaf(sg, own.y, oth.y));
    }
  }
}

// pass 1 inv: r2 (shfl) + size-32 radix-16 DIT; odd half gets conj(W32)
// input twiddles. even lane p = e+o ; odd lane p = (e-o)*conj(W32^q).
template<int T>
__device__ void inv_head32(float2* S, int tid){
  const int half = tid & 1;
  const float sg = half ? -1.f : 1.f;
  for (int v = tid >> 1; v < 256; v += (T >> 1)){
    const int base = v << 5;
    float2 p[16], X[16];
#pragma unroll
    for (int q = 0; q < 16; q++){
      float2 own = S[SW(base + 2*q + half)];
      float2 oth;
      oth.x = __shfl_xor(own.x, 1, 64);
      oth.y = __shfl_xor(own.y, 1, 64);
      p[q] = make_float2(fmaf(sg, own.x, oth.x), fmaf(sg, own.y, oth.y));
    }
    if (half){
      float2 W[16]; w32_tab(W);
#pragma unroll
      for (int q = 1; q < 16; q++) p[q] = cmulcf(p[q], W[q]);
    }
    dft16<1>(p, X);
#pragma unroll
    for (int q = 0; q < 16; q++) S[SW(base + 2*q + half)] = X[q];
  }
}

// pass 2 inv: size 512 DIT (conj input twiddles).
template<int T>
__device__ void fft_mid16_i(float2* S, int tid){
  const float ang = -6.283185307179586f / 512.f;   // fwd sense, conj at use
  for (int u = tid; u < 512; u += T){
    const int j = u & 31;
    const int base = ((u >> 5) << 9) + j;
    float2 a[16], X[16];
#pragma unroll
    for (int q = 0; q < 16; q++) a[q] = S[SW(base + (q << 5))];
    float2 W[16]; wtree16(ang * (float)j, W);
#pragma unroll
    for (int q = 1; q < 16; q++) a[q] = cmulcf(a[q], W[q]);
    dft16<1>(a, X);
#pragma unroll
    for (int q = 0; q < 16; q++) S[SW(base + (q << 5))] = X[q];
  }
}

// pass 3 inv: size 8192 DIT; only outputs q<8 (addresses < 4096) are the
// packed lower half — write them DIRECTLY to global (coalesced), skip rest.
template<int T>
__device__ void fft_last_g16(float2* S, float2* __restrict__ yb, int tid){
  const float ang = -6.283185307179586f / 8192.f;  // fwd sense, conj at use
  for (int u = tid; u < 512; u += T){
    float2 a[16], X[16];
#pragma unroll
    for (int q = 0; q < 16; q++) a[q] = S[SW(u + q*512)];
    float2 W[16]; wtree16(ang * (float)u, W);
#pragma unroll
    for (int q = 1; q < 16; q++) a[q] = cmulcf(a[q], W[q]);
    dft16<1>(a, X);
#pragma unroll
    for (int q = 0; q < 8; q++) yb[u + q*512] = X[q];
  }
}

// sigma for radices (16,16,16,2): k = e3*4096+e2*256+e1*16+e0
//   -> sig(k) = e0*512 + e1*32 + e2*2 + e3
__device__ __forceinline__ int sig8192(int k){
  return ((k & 15) << 9) | (((k >> 4) & 15) << 5) | (((k >> 8) & 15) << 1) | (k >> 12);
}
__device__ __forceinline__ int siginv_even(int m){  // k (<4096) with sig(k)==2m
  return ((m >> 8) & 15) | (((m >> 4) & 15) << 4) | ((m & 15) << 8);
}

__device__ __forceinline__ double wsum64(double v){
#pragma unroll
  for (int m = 32; m > 0; m >>= 1) v += __shfl_xor(v, m, 64);
  return v;
}

// A) wave-per-l Cauchy (fp64) -> Hermitian-forced Y[0..8191]; T via WGs>=1025
#define KHAT_CAUCHY_WGS 1025
__global__ __launch_bounds__(256) void s4_khat_kernel(const float* __restrict__ Bp,
                                                      const float* __restrict__ Cp,
                                                      double2* __restrict__ Y,
                                                      double* __restrict__ T){
  const double PI = 3.14159265358979323846264338327950288;
  const int bid = blockIdx.x;
  const int tid = threadIdx.x;
  if (bid >= KHAT_CAUCHY_WGS){
    int d = (bid - KHAT_CAUCHY_WGS) * 256 + tid;
    double phi = PI * (double)(2*d - 1) / 16384.0;
    double s, c; sincos(phi, &s, &c);
    T[d] = c / s;
    return;
  }
  const int l = bid * 4 + (tid >> 6);     // one wave per bin l
  const int n = tid & 63;                 // lane owns pole n
  if (l > 4096) return;
  double th = (2.0 * PI / 8192.0) * (double)l;
  double wr = cos(th), wi = sin(th);
  double ux = 1.0 + wr, uy = wi;
  double vx = 1.0 - wr, vy = -wi;
  double gx = 20.0 * vx, gy = 20.0 * vy;
  double Bn = (double)Bp[n], Cn = (double)Cp[n];
  double Pn = sqrt((double)n + 0.5);
  double lx = -0.5, ly = PI * (double)n;
  double dx = gx - (ux*lx - uy*ly);
  double dy = gy - (ux*ly + uy*lx);
  double inv2 = 2.0 / (dx*dx + dy*dy);
  double cix = dx * inv2, ciy = -dy * inv2;
  double w00 = Cn*Bn, w01 = Cn*Pn, w10 = Pn*Bn, w11 = Pn*Pn;
  double s00x = wsum64(w00*cix), s00y = wsum64(w00*ciy);
  double s01x = wsum64(w01*cix), s01y = wsum64(w01*ciy);
  double s10x = wsum64(w10*cix), s10y = wsum64(w10*ciy);
  double s11x = wsum64(w11*cix), s11y = wsum64(w11*ciy);
  double hux = 0.5*ux, huy = 0.5*uy;
  double k11x = hux*s11x - huy*s11y;
  double k11y = hux*s11y + huy*s11x;
  double p1x = 1.0 + k11x, p1y = k11y;
  double t1x = s01x*p1x - s01y*p1y, t1y = s01x*p1y + s01y*p1x;
  double t2x = t1x*s10x - t1y*s10y, t2y = t1x*s10y + t1y*s10x;
  double crx = t2x*hux - t2y*huy,   cry = t2x*huy + t2y*hux;
  double vr = s00x - crx, vi = s00y - cry;
  if (n == 0){
    if (l == 0 || l == 4096) Y[l] = make_double2(vr, 0.0);
    else                     Y[l] = make_double2(vr, vi);
  } else if (n == 1 && l != 0 && l != 4096){
    Y[8192 - l] = make_double2(vr, -vi);
  }
}

// B) LDS-staged Dirichlet odd bins + S_K + table writes (same math; table
// indices go through the NEW sigma, matching conv's pointwise).
__global__ __launch_bounds__(256) void s4_tabs_kernel(const double2* __restrict__ Y,
                                                      const double* __restrict__ T,
                                                      float2* __restrict__ Ta,
                                                      float2* __restrict__ Tb){
  __shared__ __align__(16) float2 Ys[8192];
  const int tid = threadIdx.x;
  const int g   = blockIdx.x;        // 0..511
  const int lA  = g * 4;
  const int lB  = 4092 - lA;
  double skr = 0.0, ski = 0.0;
  for (int m = tid; m < 8192; m += 256){
    double2 v = Y[m];
    skr += v.x; ski += v.y;
    Ys[m] = make_float2((float)v.x, (float)v.y);
  }
  __syncthreads();
  double aAr[4]={0,0,0,0}, aAi[4]={0,0,0,0};
  double aBr[4]={0,0,0,0}, aBi[4]={0,0,0,0};
#pragma unroll 4
  for (int s = 0; s < 32; s++){
    const int d = (s << 8) + tid;
    const double t = T[d];
#pragma unroll
    for (int j = 0; j < 4; j++){
      float2 va = Ys[(lA + j + d) & 8191];
      float2 vb = Ys[(lB + j + d) & 8191];
      aAr[j] += t * (double)va.x;  aAi[j] += t * (double)va.y;
      aBr[j] += t * (double)vb.x;  aBi[j] += t * (double)vb.y;
    }
  }
  __syncthreads();
  double2 (*red)[9] = (double2 (*)[9])(void*)Ys;
#pragma unroll
  for (int j = 0; j < 4; j++){
    red[tid][j]     = make_double2(aAr[j], aAi[j]);
    red[tid][4 + j] = make_double2(aBr[j], aBi[j]);
  }
  red[tid][8] = make_double2(skr, ski);
  __syncthreads();
  for (int h = 128; h > 0; h >>= 1){
    if (tid < h){
#pragma unroll
      for (int j = 0; j < 9; j++){
        red[tid][j].x += red[tid + h][j].x;
        red[tid][j].y += red[tid + h][j].y;
      }
    }
    __syncthreads();
  }
  if (tid < 4){
    const int l = lA + tid;
    const double SKr = red[0][8].x, SKi = red[0][8].y;
    const double Por = red[0][tid].x, Poi = red[0][tid].y;
    const double Pmr = red[0][4 + (3 - tid)].x, Pmi = red[0][4 + (3 - tid)].y;
    const double q = (1.0/8192.0) * (1.0/8192.0);
    int mo = sig8192(2*l + 1) >> 1;
    Ta[mo] = make_float2((float)((SKr - Poi) * q), (float)((SKi + Por) * q));
    Tb[mo] = make_float2((float)((SKr - Pmi) * q), (float)((SKi + Pmr) * q));
    const double sc = 1.0/8192.0;
    int me = sig8192(2*l) >> 1;
    double2 ye = Y[l];
    double2 yo = Y[4096 - l];
    Ta[me] = make_float2((float)(ye.x * sc), (float)(ye.y * sc));
    Tb[me] = make_float2((float)(yo.x * sc), (float)(yo.y * sc));
  }
  if (g == 0 && tid == 4){
    double2 yn = Y[2048];
    float2 v = make_float2((float)(yn.x / 8192.0), (float)(yn.y / 8192.0));
    Ta[4096] = v; Tb[4096] = v;
  }
}

// C) conv v7 — radix-16, 7 passes / 6 barriers; pointwise math unchanged.
__global__ __launch_bounds__(TPB, 4) void s4_conv_kernel(const float2* __restrict__ x2,
                                                         const float2* __restrict__ Ta,
                                                         const float2* __restrict__ Tb,
                                                         float2* __restrict__ y2){
  __shared__ __align__(16) float2 S[8192];
  const int tid = threadIdx.x;
  const int b = blockIdx.x;
  const float2* xb = x2 + (size_t)b * 4096;
  fft_first_g16<TPB>(S, xb, tid);  __syncthreads();
  fft_mid16_f<TPB>(S, tid);        __syncthreads();
  fwd_tail32<TPB>(S, tid);         __syncthreads();
  for (int m = tid; m < 4097; m += TPB){
    int s, k;
    if (m == 4096){ s = 1; k = 4096; }
    else          { s = 2*m; k = siginv_even(m); }
    int j = (8192 - k) & 8191;
    int sj = sig8192(j);
    int as = SW(s), aj = SW(sj);
    float2 Zk = S[as], Zj = S[aj];
    float2 A  = make_float2(0.5f*(Zk.x + Zj.x), 0.5f*(Zk.y - Zj.y));
    float2 Bc = make_float2(0.5f*(Zk.x - Zj.x), 0.5f*(Zk.y + Zj.y));
    float sn, cn; __sincosf(-3.834951969714103e-4f * (float)k, &sn, &cn);
    float2 tb  = cmulf(make_float2(cn, sn), Bc);
    float2 tcb = cmulf(make_float2(cn, -sn), make_float2(Bc.x, -Bc.y));
    float2 Xk = make_float2(A.x + tb.y,  A.y - tb.x);
    float2 Xm = make_float2(A.x + tcb.y, -A.y - tcb.x);
    float2 Yk = cmulf(Xk, Ta[m]);
    float2 Ym = cmulf(Xm, Tb[m]);
    float2 E = make_float2(0.5f*(Yk.x + Ym.x), 0.5f*(Yk.y - Ym.y));
    float2 D = make_float2(0.5f*(Yk.x - Ym.x), 0.5f*(Yk.y + Ym.y));
    float2 Od = cmulf(make_float2(cn, -sn), D);
    S[as] = make_float2(E.x - Od.y, E.y + Od.x);
    if (aj != as)
      S[aj] = make_float2(E.x + Od.y, Od.x - E.y);
  }
  __syncthreads();
  inv_head32<TPB>(S, tid);         __syncthreads();
  fft_mid16_i<TPB>(S, tid);        __syncthreads();
  float2* yb = y2 + (size_t)b * 4096;
  fft_last_g16<TPB>(S, yb, tid);
}

extern "C" void kernel_launch(void* const* d_in, const int* in_sizes, int n_in,
                              void* d_out, int out_size, void* d_ws, size_t ws_size,
                              hipStream_t stream){
  (void)n_in; (void)out_size; (void)ws_size;
  const float* x  = (const float*)d_in[0];
  const float* Bp = (const float*)d_in[1];
  const float* Cp = (const float*)d_in[2];
  // ws: Y[8192] double2 @0 (128K), T[8192] double @131072 (64K),
  //     Ta[4097] float2 @196608, Tb[4097] float2 @229632  (~257 KB)
  double2* Yt = (double2*)d_ws;
  double*  Tt = (double*)((char*)d_ws + 131072);
  float2*  Ta = (float2*)((char*)d_ws + 196608);
  float2*  Tb = (float2*)((char*)d_ws + 229632);
  const int batch = in_sizes[0] / 8192;
  hipLaunchKernelGGL(s4_khat_kernel, dim3(KHAT_CAUCHY_WGS + 32), dim3(256), 0, stream,
                     Bp, Cp, Yt, Tt);
  hipLaunchKernelGGL(s4_tabs_kernel, dim3(512), dim3(256), 0, stream, Yt, Tt, Ta, Tb);
  hipLaunchKernelGGL(s4_conv_kernel, dim3(batch), dim3(TPB), 0, stream,
                     (const float2*)x, Ta, Tb, (float2*)d_out);
}

// Round 7
// 146.940 us; speedup vs baseline: 1.0596x; 1.0596x over previous
//
#include <hip/hip_runtime.h>
#include <math.h>

// S4 DPLR kernel + batched causal convolution via custom packed-real FFTs.
//
//  A) s4_khat_kernel : wave-per-l Cauchy sum (byte-identical, verified).
//  B) s4_tabs_kernel : LDS-staged Dirichlet odd bins + S_K + sigma-permuted
//       pair tables (byte-identical v4 form, verified; radix-8 sigma).
//  C) s4_conv_kernel v8 : v4 STRUCTURE (best measured: 50.0us, 9 passes) with
//       ALL complex arithmetic converted to ext_vector_type(2) fp32 so the
//       backend emits VOP3P packed math (v_pk_add/mul/fma_f32 = 2 fp32
//       lanes/instr). Rationale: across v2/v4/v6/v7 the invariant is
//       dur*VALUBusy ~ 33-34us of VALU issue — the kernel is VALU-instruction
//       -count bound, and scalar float2 math runs at HALF the chip's fp32
//       issue width (157.3 TF spec = packed rate; scalar = 78.6).
//       complex add/sub: 2 instr -> 1 (pk_add); complex mul: 4 -> 2
//       (pk_mul + pk_fma; lane swap folds to op_sel, negation to neg_lo).
//       Also: pointwise tcb == conj(tb) identity (bit-identical, the
//       original computed the same partial products twice).
//       Predicted: conv 50 -> ~38-42us, VALU instrs -40%.
//
// LDS addresses go through SW(x) = x ^ ((x>>4)&15) to kill bank conflicts
// (v4's verified swizzle; SW permutes only within aligned 16-blocks).

#define TPB 512

typedef float cpx __attribute__((ext_vector_type(2)));

__device__ __forceinline__ cpx mkc(float x, float y){ cpx r; r.x = x; r.y = y; return r; }

__device__ __forceinline__ int SW(int x){ return x ^ ((x >> 4) & 15); }

// complex mul: (a.x b.x - a.y b.y, a.x b.y + a.y b.x) = a*b.x + (-a.y,a.x)*b.y
//   -> v_pk_mul_f32 + v_pk_fma_f32 (swap via op_sel, sign via neg_lo)
__device__ __forceinline__ cpx cmulf(cpx a, cpx b){
  cpx m = mkc(-a.y, a.x);
  return a * b.x + m * b.y;
}
// a * conj(b): (a.x b.x + a.y b.y, a.y b.x - a.x b.y) = a*b.x + (a.y,-a.x)*b.y
__device__ __forceinline__ cpx cmulcf(cpx a, cpx b){
  cpx m = mkc(a.y, -a.x);
  return a * b.x + m * b.y;
}
template<int SGN>
__device__ __forceinline__ cpx muli(cpx v){
  return (SGN > 0) ? mkc(-v.y, v.x) : mkc(v.y, -v.x);
}

template<int SGN>   // -1: forward DFT8; +1: conj (unscaled inverse)
__device__ __forceinline__ void dft8(const cpx* a, cpx* X){
  const float C  = 0.70710678118654752f;
  const float SC = (SGN > 0) ? C : -C;
  cpx e0=a[0]+a[4], e1=a[0]-a[4];
  cpx e2=a[2]+a[6], e3=a[2]-a[6];
  cpx f0=a[1]+a[5], f1=a[1]-a[5];
  cpx f2=a[3]+a[7], f3=a[3]-a[7];
  cpx ie3 = muli<SGN>(e3), if3 = muli<SGN>(f3);
  cpx E0=e0+e2, E2=e0-e2;
  cpx E1=e1+ie3, E3=e1-ie3;
  cpx O0=f0+f2, O2=f0-f2;
  cpx O1=f1+if3, O3=f1-if3;
  cpx O2r = muli<SGN>(O2);
  cpx O1r = cmulf(O1, mkc(C,  SC));
  cpx O3r = cmulf(O3, mkc(-C, SC));
  X[0]=E0+O0;  X[4]=E0-O0;
  X[1]=E1+O1r; X[5]=E1-O1r;
  X[2]=E2+O2r; X[6]=E2-O2r;
  X[3]=E3+O3r; X[7]=E3-O3r;
}

// W16^q = e^{-2pi i q/16}, q=0..7 (forward DIF twiddles of the size-16 stage)
__device__ __forceinline__ void w16_tab(cpx* W){
  W[0] = mkc( 1.f, 0.f);
  W[1] = mkc( 0.923879533f, -0.382683432f);
  W[2] = mkc( 0.707106781f, -0.707106781f);
  W[3] = mkc( 0.382683432f, -0.923879533f);
  W[4] = mkc( 0.f, -1.f);
  W[5] = mkc(-0.382683432f, -0.923879533f);
  W[6] = mkc(-0.707106781f, -0.707106781f);
  W[7] = mkc(-0.923879533f, -0.382683432f);
}

template<int NFFT, int T>
__device__ void dif8_stage(cpx* S, int size, int tid){
  const int t = size >> 3;
  const float ang = -6.283185307179586f / (float)size;
  for (int u = tid; u < (NFFT >> 3); u += T){
    int j = u & (t - 1);
    int base = ((u - j) << 3) + j;
    cpx a[8], X[8];
#pragma unroll
    for (int q = 0; q < 8; q++) a[q] = S[SW(base + q*t)];
    dft8<-1>(a, X);
    if (t > 1){
      float sn, cn; __sincosf(ang * (float)j, &sn, &cn);
      cpx w = mkc(cn, sn), wq = w;
#pragma unroll
      for (int q = 1; q < 8; q++){ X[q] = cmulf(X[q], wq); wq = cmulf(wq, w); }
    }
#pragma unroll
    for (int q = 0; q < 8; q++) S[SW(base + q*t)] = X[q];
  }
}

// first forward stage (size = NFFT, t = NFFT/8): thread u's butterfly
// addresses are u + q*1024 — identical to the old pack-loop addresses — so
// read x DIRECTLY from global (coalesced) and never touch the upper zero
// half (q>=4). (Verified in v3/v4.)
template<int NFFT, int T>
__device__ void dif8_first_g(cpx* S, const cpx* __restrict__ xb, int tid){
  const int t = NFFT >> 3;
  const float ang = -6.283185307179586f / (float)NFFT;
  for (int u = tid; u < t; u += T){
    cpx a[8], X[8];
#pragma unroll
    for (int q = 0; q < 4; q++) a[q] = xb[u + q*t];
#pragma unroll
    for (int q = 4; q < 8; q++) a[q] = mkc(0.f, 0.f);
    dft8<-1>(a, X);
    float sn, cn; __sincosf(ang * (float)u, &sn, &cn);
    cpx w = mkc(cn, sn), wq = w;
#pragma unroll
    for (int q = 1; q < 8; q++){ X[q] = cmulf(X[q], wq); wq = cmulf(wq, w); }
#pragma unroll
    for (int q = 0; q < 8; q++) S[SW(u + q*t)] = X[q];
  }
}

template<int NFFT, int T>
__device__ void dit8_stage(cpx* S, int size, int tid){
  const int t = size >> 3;
  const float ang = 6.283185307179586f / (float)size;
  for (int u = tid; u < (NFFT >> 3); u += T){
    int j = u & (t - 1);
    int base = ((u - j) << 3) + j;
    cpx a[8], X[8];
#pragma unroll
    for (int q = 0; q < 8; q++) a[q] = S[SW(base + q*t)];
    if (t > 1){
      float sn, cn; __sincosf(ang * (float)j, &sn, &cn);
      cpx w = mkc(cn, sn), wq = w;
#pragma unroll
      for (int q = 1; q < 8; q++){ a[q] = cmulf(a[q], wq); wq = cmulf(wq, w); }
    }
    dft8<1>(a, X);
#pragma unroll
    for (int q = 0; q < 8; q++) S[SW(base + q*t)] = X[q];
  }
}

// last inverse stage (size = NFFT): thread u's q<4 outputs land at u + q*1024
// — write y DIRECTLY to global (coalesced). (Verified in v3/v4.)
template<int NFFT, int T>
__device__ void dit8_last_g(cpx* S, cpx* __restrict__ yb, int tid){
  const int t = NFFT >> 3;
  const float ang = 6.283185307179586f / (float)NFFT;
  for (int u = tid; u < t; u += T){
    cpx a[8], X[8];
#pragma unroll
    for (int q = 0; q < 8; q++) a[q] = S[SW(u + q*t)];
    float sn, cn; __sincosf(ang * (float)u, &sn, &cn);
    cpx w = mkc(cn, sn), wq = w;
#pragma unroll
    for (int q = 1; q < 8; q++){ a[q] = cmulf(a[q], wq); wq = cmulf(wq, w); }
    dft8<1>(a, X);
#pragma unroll
    for (int q = 0; q < 4; q++) yb[u + q*t] = X[q];
  }
}

// merged dif8(size=16) + r2: thread v owns block [16v,16v+16); j=0 butterflies
// on even offsets, j=1 on odds with constant W16 twiddles, then the 8 r2 pairs
// — all in registers.
template<int T>
__device__ void fwd_tail16(cpx* S, int tid){
  cpx W[8]; w16_tab(W);
  for (int v = tid; v < 512; v += T){
    const int base = v << 4;
    const int sw = v & 15;
    cpx a0[8], a1[8], X0[8], X1[8];
#pragma unroll
    for (int q = 0; q < 8; q++){
      a0[q] = S[base + ((2*q)     ^ sw)];
      a1[q] = S[base + ((2*q + 1) ^ sw)];
    }
    dft8<-1>(a0, X0);
    dft8<-1>(a1, X1);
#pragma unroll
    for (int q = 0; q < 8; q++){
      cpx tq = cmulf(X1[q], W[q]);                 // j=1 twiddle (const)
      S[base + ((2*q)     ^ sw)] = X0[q] + tq;     // r2 sum
      S[base + ((2*q + 1) ^ sw)] = X0[q] - tq;     // r2 diff
    }
  }
}

// merged r2 + dit8(size=16): r2 pairs in registers, then the two inverse
// size-16 butterflies (j=1 inputs get conj(W16) twiddles).
template<int T>
__device__ void inv_head16(cpx* S, int tid){
  cpx W[8]; w16_tab(W);
  for (int v = tid; v < 512; v += T){
    const int base = v << 4;
    const int sw = v & 15;
    cpx p0[8], p1[8], X0[8], X1[8];
#pragma unroll
    for (int q = 0; q < 8; q++){
      cpx e = S[base + ((2*q)     ^ sw)];
      cpx o = S[base + ((2*q + 1) ^ sw)];
      p0[q] = e + o;                      // r2 -> even offsets (j=0 inputs)
      p1[q] = cmulcf(e - o, W[q]);        // r2 diff * conj(W16^q) (j=1 inputs)
    }
    dft8<1>(p0, X0);
    dft8<1>(p1, X1);
#pragma unroll
    for (int q = 0; q < 8; q++){
      S[base + ((2*q)     ^ sw)] = X0[q];   // j=0 outputs at even offsets
      S[base + ((2*q + 1) ^ sw)] = X1[q];   // j=1 outputs at odd offsets
    }
  }
}

// sigma for radices (8,8,8,8,2) — v4's verified version
__device__ __forceinline__ int sig8192(int k){
  return ((k & 7) << 10) | (((k >> 3) & 7) << 7) | (((k >> 6) & 7) << 4)
       | (((k >> 9) & 7) << 1) | ((k >> 12) & 1);
}
__device__ __forceinline__ int siginv_even(int m){  // k such that sig8192(k) == 2m
  return (m >> 9) | (((m >> 6) & 7) << 3) | (((m >> 3) & 7) << 6) | ((m & 7) << 9);
}

__device__ __forceinline__ double wsum64(double v){
#pragma unroll
  for (int m = 32; m > 0; m >>= 1) v += __shfl_xor(v, m, 64);
  return v;
}

// A) wave-per-l Cauchy (fp64) -> Hermitian-forced Y[0..8191]; T via WGs>=1025
#define KHAT_CAUCHY_WGS 1025
__global__ __launch_bounds__(256) void s4_khat_kernel(const float* __restrict__ Bp,
                                                      const float* __restrict__ Cp,
                                                      double2* __restrict__ Y,
                                                      double* __restrict__ T){
  const double PI = 3.14159265358979323846264338327950288;
  const int bid = blockIdx.x;
  const int tid = threadIdx.x;
  if (bid >= KHAT_CAUCHY_WGS){
    int d = (bid - KHAT_CAUCHY_WGS) * 256 + tid;
    double phi = PI * (double)(2*d - 1) / 16384.0;
    double s, c; sincos(phi, &s, &c);
    T[d] = c / s;
    return;
  }
  const int l = bid * 4 + (tid >> 6);     // one wave per bin l
  const int n = tid & 63;                 // lane owns pole n
  if (l > 4096) return;
  double th = (2.0 * PI / 8192.0) * (double)l;
  double wr = cos(th), wi = sin(th);
  double ux = 1.0 + wr, uy = wi;
  double vx = 1.0 - wr, vy = -wi;
  double gx = 20.0 * vx, gy = 20.0 * vy;
  double Bn = (double)Bp[n], Cn = (double)Cp[n];
  double Pn = sqrt((double)n + 0.5);
  double lx = -0.5, ly = PI * (double)n;
  double dx = gx - (ux*lx - uy*ly);
  double dy = gy - (ux*ly + uy*lx);
  double inv2 = 2.0 / (dx*dx + dy*dy);
  double cix = dx * inv2, ciy = -dy * inv2;
  double w00 = Cn*Bn, w01 = Cn*Pn, w10 = Pn*Bn, w11 = Pn*Pn;
  double s00x = wsum64(w00*cix), s00y = wsum64(w00*ciy);
  double s01x = wsum64(w01*cix), s01y = wsum64(w01*ciy);
  double s10x = wsum64(w10*cix), s10y = wsum64(w10*ciy);
  double s11x = wsum64(w11*cix), s11y = wsum64(w11*ciy);
  double hux = 0.5*ux, huy = 0.5*uy;
  double k11x = hux*s11x - huy*s11y;
  double k11y = hux*s11y + huy*s11x;
  double p1x = 1.0 + k11x, p1y = k11y;
  double t1x = s01x*p1x - s01y*p1y, t1y = s01x*p1y + s01y*p1x;
  double t2x = t1x*s10x - t1y*s10y, t2y = t1x*s10y + t1y*s10x;
  double crx = t2x*hux - t2y*huy,   cry = t2x*huy + t2y*hux;
  double vr = s00x - crx, vi = s00y - cry;
  if (n == 0){
    if (l == 0 || l == 4096) Y[l] = make_double2(vr, 0.0);
    else                     Y[l] = make_double2(vr, vi);
  } else if (n == 1 && l != 0 && l != 4096){
    Y[8192 - l] = make_double2(vr, -vi);
  }
}

// B) LDS-staged Dirichlet odd bins + S_K + table writes — v4 form, verified
__global__ __launch_bounds__(256) void s4_tabs_kernel(const double2* __restrict__ Y,
                                                      const double* __restrict__ T,
                                                      float2* __restrict__ Ta,
                                                      float2* __restrict__ Tb){
  __shared__ __align__(16) float2 Ys[8192];
  const int tid = threadIdx.x;
  const int g   = blockIdx.x;        // 0..511
  const int lA  = g * 4;
  const int lB  = 4092 - lA;
  double skr = 0.0, ski = 0.0;
  for (int m = tid; m < 8192; m += 256){
    double2 v = Y[m];
    skr += v.x; ski += v.y;
    Ys[m] = make_float2((float)v.x, (float)v.y);
  }
  __syncthreads();
  double aAr[4]={0,0,0,0}, aAi[4]={0,0,0,0};
  double aBr[4]={0,0,0,0}, aBi[4]={0,0,0,0};
#pragma unroll 4
  for (int s = 0; s < 32; s++){
    const int d = (s << 8) + tid;
    const double t = T[d];
#pragma unroll
    for (int j = 0; j < 4; j++){
      float2 va = Ys[(lA + j + d) & 8191];
      float2 vb = Ys[(lB + j + d) & 8191];
      aAr[j] += t * (double)va.x;  aAi[j] += t * (double)va.y;
      aBr[j] += t * (double)vb.x;  aBi[j] += t * (double)vb.y;
    }
  }
  __syncthreads();
  double2 (*red)[9] = (double2 (*)[9])(void*)Ys;
#pragma unroll
  for (int j = 0; j < 4; j++){
    red[tid][j]     = make_double2(aAr[j], aAi[j]);
    red[tid][4 + j] = make_double2(aBr[j], aBi[j]);
  }
  red[tid][8] = make_double2(skr, ski);
  __syncthreads();
  for (int h = 128; h > 0; h >>= 1){
    if (tid < h){
#pragma unroll
      for (int j = 0; j < 9; j++){
        red[tid][j].x += red[tid + h][j].x;
        red[tid][j].y += red[tid + h][j].y;
      }
    }
    __syncthreads();
  }
  if (tid < 4){
    const int l = lA + tid;
    const double SKr = red[0][8].x, SKi = red[0][8].y;
    const double Por = red[0][tid].x, Poi = red[0][tid].y;
    const double Pmr = red[0][4 + (3 - tid)].x, Pmi = red[0][4 + (3 - tid)].y;
    const double q = (1.0/8192.0) * (1.0/8192.0);
    int mo = sig8192(2*l + 1) >> 1;
    Ta[mo] = make_float2((float)((SKr - Poi) * q), (float)((SKi + Por) * q));
    Tb[mo] = make_float2((float)((SKr - Pmi) * q), (float)((SKi + Pmr) * q));
    const double sc = 1.0/8192.0;
    int me = sig8192(2*l) >> 1;
    double2 ye = Y[l];
    double2 yo = Y[4096 - l];
    Ta[me] = make_float2((float)(ye.x * sc), (float)(ye.y * sc));
    Tb[me] = make_float2((float)(yo.x * sc), (float)(yo.y * sc));
  }
  if (g == 0 && tid == 4){
    double2 yn = Y[2048];
    float2 v = make_float2((float)(yn.x / 8192.0), (float)(yn.y / 8192.0));
    Ta[4096] = v; Tb[4096] = v;
  }
}

// C) conv v8 — v4 structure, packed-fp32 complex arithmetic throughout.
__global__ __launch_bounds__(TPB, 4) void s4_conv_kernel(const cpx* __restrict__ x2,
                                                         const cpx* __restrict__ Ta,
                                                         const cpx* __restrict__ Tb,
                                                         cpx* __restrict__ y2){
  __shared__ __align__(16) cpx S[8192];
  const int tid = threadIdx.x;
  const int b = blockIdx.x;
  const cpx* xb = x2 + (size_t)b * 4096;
  dif8_first_g<8192,TPB>(S, xb, tid);  __syncthreads();
  dif8_stage<8192,TPB>(S, 1024, tid);  __syncthreads();
  dif8_stage<8192,TPB>(S, 128, tid);   __syncthreads();
  fwd_tail16<TPB>(S, tid);             __syncthreads();
  for (int m = tid; m < 4097; m += TPB){
    int s, k;
    if (m == 4096){ s = 1; k = 4096; }
    else          { s = 2*m; k = siginv_even(m); }
    int j = (8192 - k) & 8191;
    int sj = sig8192(j);
    int as = SW(s), aj = SW(sj);
    cpx Zk = S[as], Zj = S[aj];
    cpx cZj = mkc(Zj.x, -Zj.y);
    cpx A  = 0.5f * (Zk + cZj);
    cpx Bc = 0.5f * (Zk - cZj);
    float sn, cn; __sincosf(-3.834951969714103e-4f * (float)k, &sn, &cn);
    cpx tb = cmulf(mkc(cn, sn), Bc);
    // tcb == conj(tb) exactly (same partial products) — folded below.
    cpx Xk = mkc(A.x + tb.y,  A.y - tb.x);
    cpx Xm = mkc(A.x - tb.y, -A.y - tb.x);
    cpx Yk = cmulf(Xk, Ta[m]);
    cpx Ym = cmulf(Xm, Tb[m]);
    cpx cYm = mkc(Ym.x, -Ym.y);
    cpx E = 0.5f * (Yk + cYm);
    cpx D = 0.5f * (Yk - cYm);
    cpx Od = cmulf(mkc(cn, -sn), D);
    S[as] = mkc(E.x - Od.y, E.y + Od.x);
    if (aj != as)
      S[aj] = mkc(E.x + Od.y, Od.x - E.y);
  }
  __syncthreads();
  inv_head16<TPB>(S, tid);             __syncthreads();
  dit8_stage<8192,TPB>(S, 128, tid);   __syncthreads();
  dit8_stage<8192,TPB>(S, 1024, tid);  __syncthreads();
  cpx* yb = y2 + (size_t)b * 4096;
  dit8_last_g<8192,TPB>(S, yb, tid);
}

extern "C" void kernel_launch(void* const* d_in, const int* in_sizes, int n_in,
                              void* d_out, int out_size, void* d_ws, size_t ws_size,
                              hipStream_t stream){
  (void)n_in; (void)out_size; (void)ws_size;
  const float* x  = (const float*)d_in[0];
  const float* Bp = (const float*)d_in[1];
  const float* Cp = (const float*)d_in[2];
  // ws: Y[8192] double2 @0 (128K), T[8192] double @131072 (64K),
  //     Ta[4097] float2 @196608, Tb[4097] float2 @229632  (~257 KB)
  double2* Yt = (double2*)d_ws;
  double*  Tt = (double*)((char*)d_ws + 131072);
  float2*  Ta = (float2*)((char*)d_ws + 196608);
  float2*  Tb = (float2*)((char*)d_ws + 229632);
  const int batch = in_sizes[0] / 8192;
  hipLaunchKernelGGL(s4_khat_kernel, dim3(KHAT_CAUCHY_WGS + 32), dim3(256), 0, stream,
                     Bp, Cp, Yt, Tt);
  hipLaunchKernelGGL(s4_tabs_kernel, dim3(512), dim3(256), 0, stream, Yt, Tt, Ta, Tb);
  hipLaunchKernelGGL(s4_conv_kernel, dim3(batch), dim3(TPB), 0, stream,
                     (const cpx*)x, (const cpx*)Ta, (const cpx*)Tb, (cpx*)d_out);
}

// Round 8
// 146.254 us; speedup vs baseline: 1.0645x; 1.0047x over previous
//
#include <hip/hip_runtime.h>
#include <math.h>

// S4 DPLR kernel + batched causal convolution via custom packed-real FFTs.
//
//  A) s4_khat_kernel : wave-per-l Cauchy sum (byte-identical, verified).
//  B) s4_tabs_kernel : LDS-staged Dirichlet odd bins + S_K + sigma-permuted
//       pair tables (byte-identical v4 form, verified; radix-8 sigma).
//  C) s4_conv_kernel v9 : v8 (packed-fp32 math, verified 48.4us) +
//       IMMEDIATE-OFFSET ADDRESSING. v8 post-mortem: packed math cut dur only
//       3% because ~40% of VALU issue is integer address calc (16 LDS
//       accesses/butterfly x {SW, +q*t, byte shift}). SW only XORs bits 0-3
//       with bits 4-7, so for stage strides that leave bits 4-7 unchanged the
//       swizzled address is AFFINE in q:
//         t=1024: SW(u+q*1024) = SW(u) + q*1024          -> 1 base, 8 imms
//         t=128 : SW(base+q*128) = (base^s0^((q&1)<<3)) + q*128
//                                                         -> 2 bases, 8 imms
//         t=16  : addr_q = (base&~15) + 16q + (jj^q), jj=(base&15)^((base>>4)&8)
//                                                         -> 8 addrs, 2 ops each,
//                                                            computed once, reused
//         tail16: odd addr = even addr ^ 1
//       ds offset immediates max 7*8192B = 57344 < 64K. Math byte-identical
//       to v8 (dft8/twiddle-chain/pointwise untouched).
//
// LDS addresses go through SW(x) = x ^ ((x>>4)&15) to kill bank conflicts
// (v4's verified swizzle; SW permutes only within aligned 16-blocks).

#define TPB 512

typedef float cpx __attribute__((ext_vector_type(2)));

__device__ __forceinline__ cpx mkc(float x, float y){ cpx r; r.x = x; r.y = y; return r; }

__device__ __forceinline__ int SW(int x){ return x ^ ((x >> 4) & 15); }

// complex mul: a*b = a*b.x + (-a.y,a.x)*b.y  (v_pk_mul + v_pk_fma)
__device__ __forceinline__ cpx cmulf(cpx a, cpx b){
  cpx m = mkc(-a.y, a.x);
  return a * b.x + m * b.y;
}
// a * conj(b)
__device__ __forceinline__ cpx cmulcf(cpx a, cpx b){
  cpx m = mkc(a.y, -a.x);
  return a * b.x + m * b.y;
}
template<int SGN>
__device__ __forceinline__ cpx muli(cpx v){
  return (SGN > 0) ? mkc(-v.y, v.x) : mkc(v.y, -v.x);
}

template<int SGN>   // -1: forward DFT8; +1: conj (unscaled inverse)
__device__ __forceinline__ void dft8(const cpx* a, cpx* X){
  const float C  = 0.70710678118654752f;
  const float SC = (SGN > 0) ? C : -C;
  cpx e0=a[0]+a[4], e1=a[0]-a[4];
  cpx e2=a[2]+a[6], e3=a[2]-a[6];
  cpx f0=a[1]+a[5], f1=a[1]-a[5];
  cpx f2=a[3]+a[7], f3=a[3]-a[7];
  cpx ie3 = muli<SGN>(e3), if3 = muli<SGN>(f3);
  cpx E0=e0+e2, E2=e0-e2;
  cpx E1=e1+ie3, E3=e1-ie3;
  cpx O0=f0+f2, O2=f0-f2;
  cpx O1=f1+if3, O3=f1-if3;
  cpx O2r = muli<SGN>(O2);
  cpx O1r = cmulf(O1, mkc(C,  SC));
  cpx O3r = cmulf(O3, mkc(-C, SC));
  X[0]=E0+O0;  X[4]=E0-O0;
  X[1]=E1+O1r; X[5]=E1-O1r;
  X[2]=E2+O2r; X[6]=E2-O2r;
  X[3]=E3+O3r; X[7]=E3-O3r;
}

// W16^q = e^{-2pi i q/16}, q=0..7
__device__ __forceinline__ void w16_tab(cpx* W){
  W[0] = mkc( 1.f, 0.f);
  W[1] = mkc( 0.923879533f, -0.382683432f);
  W[2] = mkc( 0.707106781f, -0.707106781f);
  W[3] = mkc( 0.382683432f, -0.923879533f);
  W[4] = mkc( 0.f, -1.f);
  W[5] = mkc(-0.382683432f, -0.923879533f);
  W[6] = mkc(-0.707106781f, -0.707106781f);
  W[7] = mkc(-0.923879533f, -0.382683432f);
}

// first forward stage (t=1024): global reads at u+q*1024 (q<4; upper half is
// the zero padding), LDS writes at SW(u)+q*1024 — single base + immediates.
template<int T>
__device__ void dif8_first_g(cpx* S, const cpx* __restrict__ xb, int tid){
  const float ang = -6.283185307179586f / 8192.f;
  for (int u = tid; u < 1024; u += T){
    cpx* p = S + SW(u);
    cpx a[8], X[8];
#pragma unroll
    for (int q = 0; q < 4; q++) a[q] = xb[u + q*1024];
#pragma unroll
    for (int q = 4; q < 8; q++) a[q] = mkc(0.f, 0.f);
    dft8<-1>(a, X);
    float sn, cn; __sincosf(ang * (float)u, &sn, &cn);
    cpx w = mkc(cn, sn), wq = w;
#pragma unroll
    for (int q = 1; q < 8; q++){ X[q] = cmulf(X[q], wq); wq = cmulf(wq, w); }
#pragma unroll
    for (int q = 0; q < 8; q++) p[q*1024] = X[q];
  }
}

// size-1024 fwd stage (t=128): 2 bases (q parity), immediate offsets.
template<int T>
__device__ void dif8_s1024(cpx* S, int tid){
  const float ang = -6.283185307179586f / 1024.f;
  for (int u = tid; u < 1024; u += T){
    int j = u & 127;
    int base = ((u - j) << 3) + j;
    cpx* pe = S + (base ^ ((j >> 4) & 7));
    cpx* po = S + ((base ^ ((j >> 4) & 7)) ^ 8);
    cpx a[8], X[8];
    a[0]=pe[0];   a[1]=po[128]; a[2]=pe[256]; a[3]=po[384];
    a[4]=pe[512]; a[5]=po[640]; a[6]=pe[768]; a[7]=po[896];
    dft8<-1>(a, X);
    float sn, cn; __sincosf(ang * (float)j, &sn, &cn);
    cpx w = mkc(cn, sn), wq = w;
#pragma unroll
    for (int q = 1; q < 8; q++){ X[q] = cmulf(X[q], wq); wq = cmulf(wq, w); }
    pe[0]=X[0];   po[128]=X[1]; pe[256]=X[2]; po[384]=X[3];
    pe[512]=X[4]; po[640]=X[5]; pe[768]=X[6]; po[896]=X[7];
  }
}

// size-128 fwd stage (t=16): 8 addrs at 2 ops each, computed once & reused.
template<int T>
__device__ void dif8_s128(cpx* S, int tid){
  const float ang = -6.283185307179586f / 128.f;
  for (int u = tid; u < 1024; u += T){
    int j = u & 15;
    int base = ((u - j) << 3) + j;
    int B  = base & ~15;
    int jj = (base & 15) ^ ((base >> 4) & 8);
    int ad[8];
#pragma unroll
    for (int q = 0; q < 8; q++) ad[q] = B + (q << 4) + (jj ^ q);
    cpx a[8], X[8];
#pragma unroll
    for (int q = 0; q < 8; q++) a[q] = S[ad[q]];
    dft8<-1>(a, X);
    float sn, cn; __sincosf(ang * (float)j, &sn, &cn);
    cpx w = mkc(cn, sn), wq = w;
#pragma unroll
    for (int q = 1; q < 8; q++){ X[q] = cmulf(X[q], wq); wq = cmulf(wq, w); }
#pragma unroll
    for (int q = 0; q < 8; q++) S[ad[q]] = X[q];
  }
}

// size-128 inv stage (t=16)
template<int T>
__device__ void dit8_s128(cpx* S, int tid){
  const float ang = 6.283185307179586f / 128.f;
  for (int u = tid; u < 1024; u += T){
    int j = u & 15;
    int base = ((u - j) << 3) + j;
    int B  = base & ~15;
    int jj = (base & 15) ^ ((base >> 4) & 8);
    int ad[8];
#pragma unroll
    for (int q = 0; q < 8; q++) ad[q] = B + (q << 4) + (jj ^ q);
    cpx a[8], X[8];
#pragma unroll
    for (int q = 0; q < 8; q++) a[q] = S[ad[q]];
    float sn, cn; __sincosf(ang * (float)j, &sn, &cn);
    cpx w = mkc(cn, sn), wq = w;
#pragma unroll
    for (int q = 1; q < 8; q++){ a[q] = cmulf(a[q], wq); wq = cmulf(wq, w); }
    dft8<1>(a, X);
#pragma unroll
    for (int q = 0; q < 8; q++) S[ad[q]] = X[q];
  }
}

// size-1024 inv stage (t=128)
template<int T>
__device__ void dit8_s1024(cpx* S, int tid){
  const float ang = 6.283185307179586f / 1024.f;
  for (int u = tid; u < 1024; u += T){
    int j = u & 127;
    int base = ((u - j) << 3) + j;
    cpx* pe = S + (base ^ ((j >> 4) & 7));
    cpx* po = S + ((base ^ ((j >> 4) & 7)) ^ 8);
    cpx a[8], X[8];
    a[0]=pe[0];   a[1]=po[128]; a[2]=pe[256]; a[3]=po[384];
    a[4]=pe[512]; a[5]=po[640]; a[6]=pe[768]; a[7]=po[896];
    float sn, cn; __sincosf(ang * (float)j, &sn, &cn);
    cpx w = mkc(cn, sn), wq = w;
#pragma unroll
    for (int q = 1; q < 8; q++){ a[q] = cmulf(a[q], wq); wq = cmulf(wq, w); }
    dft8<1>(a, X);
    pe[0]=X[0];   po[128]=X[1]; pe[256]=X[2]; po[384]=X[3];
    pe[512]=X[4]; po[640]=X[5]; pe[768]=X[6]; po[896]=X[7];
  }
}

// last inverse stage (t=1024): LDS reads at SW(u)+q*1024 (1 base, immediates),
// only q<4 outputs written DIRECTLY to global (coalesced).
template<int T>
__device__ void dit8_last_g(cpx* S, cpx* __restrict__ yb, int tid){
  const float ang = 6.283185307179586f / 8192.f;
  for (int u = tid; u < 1024; u += T){
    cpx* p = S + SW(u);
    cpx a[8], X[8];
#pragma unroll
    for (int q = 0; q < 8; q++) a[q] = p[q*1024];
    float sn, cn; __sincosf(ang * (float)u, &sn, &cn);
    cpx w = mkc(cn, sn), wq = w;
#pragma unroll
    for (int q = 1; q < 8; q++){ a[q] = cmulf(a[q], wq); wq = cmulf(wq, w); }
    dft8<1>(a, X);
#pragma unroll
    for (int q = 0; q < 4; q++) yb[u + q*1024] = X[q];
  }
}

// merged dif8(size=16) + r2: thread v owns block [16v,16v+16); odd address =
// even address ^ 1; addresses computed once & reused.
template<int T>
__device__ void fwd_tail16(cpx* S, int tid){
  cpx W[8]; w16_tab(W);
  for (int v = tid; v < 512; v += T){
    const int base = v << 4;
    const int sw = v & 15;
    int ae[8];
#pragma unroll
    for (int q = 0; q < 8; q++) ae[q] = base + ((2*q) ^ sw);
    cpx a0[8], a1[8], X0[8], X1[8];
#pragma unroll
    for (int q = 0; q < 8; q++){
      a0[q] = S[ae[q]];
      a1[q] = S[ae[q] ^ 1];
    }
    dft8<-1>(a0, X0);
    dft8<-1>(a1, X1);
#pragma unroll
    for (int q = 0; q < 8; q++){
      cpx tq = cmulf(X1[q], W[q]);          // j=1 twiddle (const)
      S[ae[q]]     = X0[q] + tq;            // r2 sum
      S[ae[q] ^ 1] = X0[q] - tq;            // r2 diff
    }
  }
}

// merged r2 + dit8(size=16)
template<int T>
__device__ void inv_head16(cpx* S, int tid){
  cpx W[8]; w16_tab(W);
  for (int v = tid; v < 512; v += T){
    const int base = v << 4;
    const int sw = v & 15;
    int ae[8];
#pragma unroll
    for (int q = 0; q < 8; q++) ae[q] = base + ((2*q) ^ sw);
    cpx p0[8], p1[8], X0[8], X1[8];
#pragma unroll
    for (int q = 0; q < 8; q++){
      cpx e = S[ae[q]];
      cpx o = S[ae[q] ^ 1];
      p0[q] = e + o;                      // r2 -> even offsets (j=0 inputs)
      p1[q] = cmulcf(e - o, W[q]);        // r2 diff * conj(W16^q) (j=1 inputs)
    }
    dft8<1>(p0, X0);
    dft8<1>(p1, X1);
#pragma unroll
    for (int q = 0; q < 8; q++){
      S[ae[q]]     = X0[q];
      S[ae[q] ^ 1] = X1[q];
    }
  }
}

// sigma for radices (8,8,8,8,2) — v4's verified version
__device__ __forceinline__ int sig8192(int k){
  return ((k & 7) << 10) | (((k >> 3) & 7) << 7) | (((k >> 6) & 7) << 4)
       | (((k >> 9) & 7) << 1) | ((k >> 12) & 1);
}
__device__ __forceinline__ int siginv_even(int m){  // k such that sig8192(k) == 2m
  return (m >> 9) | (((m >> 6) & 7) << 3) | (((m >> 3) & 7) << 6) | ((m & 7) << 9);
}

__device__ __forceinline__ double wsum64(double v){
#pragma unroll
  for (int m = 32; m > 0; m >>= 1) v += __shfl_xor(v, m, 64);
  return v;
}

// A) wave-per-l Cauchy (fp64) -> Hermitian-forced Y[0..8191]; T via WGs>=1025
#define KHAT_CAUCHY_WGS 1025
__global__ __launch_bounds__(256) void s4_khat_kernel(const float* __restrict__ Bp,
                                                      const float* __restrict__ Cp,
                                                      double2* __restrict__ Y,
                                                      double* __restrict__ T){
  const double PI = 3.14159265358979323846264338327950288;
  const int bid = blockIdx.x;
  const int tid = threadIdx.x;
  if (bid >= KHAT_CAUCHY_WGS){
    int d = (bid - KHAT_CAUCHY_WGS) * 256 + tid;
    double phi = PI * (double)(2*d - 1) / 16384.0;
    double s, c; sincos(phi, &s, &c);
    T[d] = c / s;
    return;
  }
  const int l = bid * 4 + (tid >> 6);     // one wave per bin l
  const int n = tid & 63;                 // lane owns pole n
  if (l > 4096) return;
  double th = (2.0 * PI / 8192.0) * (double)l;
  double wr = cos(th), wi = sin(th);
  double ux = 1.0 + wr, uy = wi;
  double vx = 1.0 - wr, vy = -wi;
  double gx = 20.0 * vx, gy = 20.0 * vy;
  double Bn = (double)Bp[n], Cn = (double)Cp[n];
  double Pn = sqrt((double)n + 0.5);
  double lx = -0.5, ly = PI * (double)n;
  double dx = gx - (ux*lx - uy*ly);
  double dy = gy - (ux*ly + uy*lx);
  double inv2 = 2.0 / (dx*dx + dy*dy);
  double cix = dx * inv2, ciy = -dy * inv2;
  double w00 = Cn*Bn, w01 = Cn*Pn, w10 = Pn*Bn, w11 = Pn*Pn;
  double s00x = wsum64(w00*cix), s00y = wsum64(w00*ciy);
  double s01x = wsum64(w01*cix), s01y = wsum64(w01*ciy);
  double s10x = wsum64(w10*cix), s10y = wsum64(w10*ciy);
  double s11x = wsum64(w11*cix), s11y = wsum64(w11*ciy);
  double hux = 0.5*ux, huy = 0.5*uy;
  double k11x = hux*s11x - huy*s11y;
  double k11y = hux*s11y + huy*s11x;
  double p1x = 1.0 + k11x, p1y = k11y;
  double t1x = s01x*p1x - s01y*p1y, t1y = s01x*p1y + s01y*p1x;
  double t2x = t1x*s10x - t1y*s10y, t2y = t1x*s10y + t1y*s10x;
  double crx = t2x*hux - t2y*huy,   cry = t2x*huy + t2y*hux;
  double vr = s00x - crx, vi = s00y - cry;
  if (n == 0){
    if (l == 0 || l == 4096) Y[l] = make_double2(vr, 0.0);
    else                     Y[l] = make_double2(vr, vi);
  } else if (n == 1 && l != 0 && l != 4096){
    Y[8192 - l] = make_double2(vr, -vi);
  }
}

// B) LDS-staged Dirichlet odd bins + S_K + table writes — v4 form, verified
__global__ __launch_bounds__(256) void s4_tabs_kernel(const double2* __restrict__ Y,
                                                      const double* __restrict__ T,
                                                      float2* __restrict__ Ta,
                                                      float2* __restrict__ Tb){
  __shared__ __align__(16) float2 Ys[8192];
  const int tid = threadIdx.x;
  const int g   = blockIdx.x;        // 0..511
  const int lA  = g * 4;
  const int lB  = 4092 - lA;
  double skr = 0.0, ski = 0.0;
  for (int m = tid; m < 8192; m += 256){
    double2 v = Y[m];
    skr += v.x; ski += v.y;
    Ys[m] = make_float2((float)v.x, (float)v.y);
  }
  __syncthreads();
  double aAr[4]={0,0,0,0}, aAi[4]={0,0,0,0};
  double aBr[4]={0,0,0,0}, aBi[4]={0,0,0,0};
#pragma unroll 4
  for (int s = 0; s < 32; s++){
    const int d = (s << 8) + tid;
    const double t = T[d];
#pragma unroll
    for (int j = 0; j < 4; j++){
      float2 va = Ys[(lA + j + d) & 8191];
      float2 vb = Ys[(lB + j + d) & 8191];
      aAr[j] += t * (double)va.x;  aAi[j] += t * (double)va.y;
      aBr[j] += t * (double)vb.x;  aBi[j] += t * (double)vb.y;
    }
  }
  __syncthreads();
  double2 (*red)[9] = (double2 (*)[9])(void*)Ys;
#pragma unroll
  for (int j = 0; j < 4; j++){
    red[tid][j]     = make_double2(aAr[j], aAi[j]);
    red[tid][4 + j] = make_double2(aBr[j], aBi[j]);
  }
  red[tid][8] = make_double2(skr, ski);
  __syncthreads();
  for (int h = 128; h > 0; h >>= 1){
    if (tid < h){
#pragma unroll
      for (int j = 0; j < 9; j++){
        red[tid][j].x += red[tid + h][j].x;
        red[tid][j].y += red[tid + h][j].y;
      }
    }
    __syncthreads();
  }
  if (tid < 4){
    const int l = lA + tid;
    const double SKr = red[0][8].x, SKi = red[0][8].y;
    const double Por = red[0][tid].x, Poi = red[0][tid].y;
    const double Pmr = red[0][4 + (3 - tid)].x, Pmi = red[0][4 + (3 - tid)].y;
    const double q = (1.0/8192.0) * (1.0/8192.0);
    int mo = sig8192(2*l + 1) >> 1;
    Ta[mo] = make_float2((float)((SKr - Poi) * q), (float)((SKi + Por) * q));
    Tb[mo] = make_float2((float)((SKr - Pmi) * q), (float)((SKi + Pmr) * q));
    const double sc = 1.0/8192.0;
    int me = sig8192(2*l) >> 1;
    double2 ye = Y[l];
    double2 yo = Y[4096 - l];
    Ta[me] = make_float2((float)(ye.x * sc), (float)(ye.y * sc));
    Tb[me] = make_float2((float)(yo.x * sc), (float)(yo.y * sc));
  }
  if (g == 0 && tid == 4){
    double2 yn = Y[2048];
    float2 v = make_float2((float)(yn.x / 8192.0), (float)(yn.y / 8192.0));
    Ta[4096] = v; Tb[4096] = v;
  }
}

// C) conv v9 — v8 math, immediate-offset addressing per stage.
__global__ __launch_bounds__(TPB, 4) void s4_conv_kernel(const cpx* __restrict__ x2,
                                                         const cpx* __restrict__ Ta,
                                                         const cpx* __restrict__ Tb,
                                                         cpx* __restrict__ y2){
  __shared__ __align__(16) cpx S[8192];
  const int tid = threadIdx.x;
  const int b = blockIdx.x;
  const cpx* xb = x2 + (size_t)b * 4096;
  dif8_first_g<TPB>(S, xb, tid);  __syncthreads();
  dif8_s1024<TPB>(S, tid);        __syncthreads();
  dif8_s128<TPB>(S, tid);         __syncthreads();
  fwd_tail16<TPB>(S, tid);        __syncthreads();
  for (int m = tid; m < 4097; m += TPB){
    int s, k;
    if (m == 4096){ s = 1; k = 4096; }
    else          { s = 2*m; k = siginv_even(m); }
    int j = (8192 - k) & 8191;
    int sj = sig8192(j);
    int as = SW(s), aj = SW(sj);
    cpx Zk = S[as], Zj = S[aj];
    cpx cZj = mkc(Zj.x, -Zj.y);
    cpx A  = 0.5f * (Zk + cZj);
    cpx Bc = 0.5f * (Zk - cZj);
    float sn, cn; __sincosf(-3.834951969714103e-4f * (float)k, &sn, &cn);
    cpx tb = cmulf(mkc(cn, sn), Bc);
    // tcb == conj(tb) exactly (same partial products) — folded.
    cpx Xk = mkc(A.x + tb.y,  A.y - tb.x);
    cpx Xm = mkc(A.x - tb.y, -A.y - tb.x);
    cpx Yk = cmulf(Xk, Ta[m]);
    cpx Ym = cmulf(Xm, Tb[m]);
    cpx cYm = mkc(Ym.x, -Ym.y);
    cpx E = 0.5f * (Yk + cYm);
    cpx D = 0.5f * (Yk - cYm);
    cpx Od = cmulf(mkc(cn, -sn), D);
    S[as] = mkc(E.x - Od.y, E.y + Od.x);
    if (aj != as)
      S[aj] = mkc(E.x + Od.y, Od.x - E.y);
  }
  __syncthreads();
  inv_head16<TPB>(S, tid);        __syncthreads();
  dit8_s128<TPB>(S, tid);         __syncthreads();
  dit8_s1024<TPB>(S, tid);        __syncthreads();
  cpx* yb = y2 + (size_t)b * 4096;
  dit8_last_g<TPB>(S, yb, tid);
}

extern "C" void kernel_launch(void* const* d_in, const int* in_sizes, int n_in,
                              void* d_out, int out_size, void* d_ws, size_t ws_size,
                              hipStream_t stream){
  (void)n_in; (void)out_size; (void)ws_size;
  const float* x  = (const float*)d_in[0];
  const float* Bp = (const float*)d_in[1];
  const float* Cp = (const float*)d_in[2];
  // ws: Y[8192] double2 @0 (128K), T[8192] double @131072 (64K),
  //     Ta[4097] float2 @196608, Tb[4097] float2 @229632  (~257 KB)
  double2* Yt = (double2*)d_ws;
  double*  Tt = (double*)((char*)d_ws + 131072);
  float2*  Ta = (float2*)((char*)d_ws + 196608);
  float2*  Tb = (float2*)((char*)d_ws + 229632);
  const int batch = in_sizes[0] / 8192;
  hipLaunchKernelGGL(s4_khat_kernel, dim3(KHAT_CAUCHY_WGS + 32), dim3(256), 0, stream,
                     Bp, Cp, Yt, Tt);
  hipLaunchKernelGGL(s4_tabs_kernel, dim3(512), dim3(256), 0, stream, Yt, Tt, Ta, Tb);
  hipLaunchKernelGGL(s4_conv_kernel, dim3(batch), dim3(TPB), 0, stream,
                     (const cpx*)x, (const cpx*)Ta, (const cpx*)Tb, (cpx*)d_out);
}

// Round 9
// 144.800 us; speedup vs baseline: 1.0752x; 1.0100x over previous
//
#include <hip/hip_runtime.h>
#include <math.h>

// S4 DPLR kernel + batched causal convolution via custom packed-real FFTs.
//
//  A) s4_khat_kernel : wave-per-l Cauchy sum (byte-identical, verified).
//  B) s4_tabs_kernel : LDS-staged Dirichlet odd bins + S_K + sigma-permuted
//       pair tables (byte-identical v4 form, verified; radix-8 sigma).
//  C) s4_conv_kernel v10 : v9 math/addressing (packed fp32 + linear swizzled
//       addresses, verified 47us, VGPR=52) at TPB=1024 / launch_bounds(1024,8).
//       Rationale: VALUBusy has been pinned at ~63-68% across every schedule
//       variant — issue starvation at 4 waves/SIMD (2 WGs x 512thr, LDS cap).
//       TPB=1024 packs 2 WGs x 1024thr = 8 waves/SIMD (LDS 2x64KB=128<=160KB).
//       v3 tested this and spilled ONLY because the scalar code needed ~60
//       VGPRs vs the 64 cap; v9's packed+linear rewrite sits at 52 <= 64.
//       Tails use the v3-verified PAIR-SPLIT (shfl_xor(1) r2 exchange, fma
//       with +-1.0 = bit-identical) which also halves tail reg pressure.
//       REVERT CONDITION: VGPR=64 + inflated hbm_bytes => spilled => back to v9.
//
// LDS addresses go through SW(x) = x ^ ((x>>4)&15) (verified swizzle), made
// affine per stage: t=1024 -> 1 base + imms; t=128 -> 2 bases (q parity);
// t=16 -> 8 addrs at 2 ops; tail odd addr = even addr ^ 1.

#define TPB 1024

typedef float cpx __attribute__((ext_vector_type(2)));

__device__ __forceinline__ cpx mkc(float x, float y){ cpx r; r.x = x; r.y = y; return r; }

__device__ __forceinline__ int SW(int x){ return x ^ ((x >> 4) & 15); }

// complex mul: a*b = a*b.x + (-a.y,a.x)*b.y  (v_pk_mul + v_pk_fma)
__device__ __forceinline__ cpx cmulf(cpx a, cpx b){
  cpx m = mkc(-a.y, a.x);
  return a * b.x + m * b.y;
}
// a * conj(b)
__device__ __forceinline__ cpx cmulcf(cpx a, cpx b){
  cpx m = mkc(a.y, -a.x);
  return a * b.x + m * b.y;
}
template<int SGN>
__device__ __forceinline__ cpx muli(cpx v){
  return (SGN > 0) ? mkc(-v.y, v.x) : mkc(v.y, -v.x);
}

template<int SGN>   // -1: forward DFT8; +1: conj (unscaled inverse)
__device__ __forceinline__ void dft8(const cpx* a, cpx* X){
  const float C  = 0.70710678118654752f;
  const float SC = (SGN > 0) ? C : -C;
  cpx e0=a[0]+a[4], e1=a[0]-a[4];
  cpx e2=a[2]+a[6], e3=a[2]-a[6];
  cpx f0=a[1]+a[5], f1=a[1]-a[5];
  cpx f2=a[3]+a[7], f3=a[3]-a[7];
  cpx ie3 = muli<SGN>(e3), if3 = muli<SGN>(f3);
  cpx E0=e0+e2, E2=e0-e2;
  cpx E1=e1+ie3, E3=e1-ie3;
  cpx O0=f0+f2, O2=f0-f2;
  cpx O1=f1+if3, O3=f1-if3;
  cpx O2r = muli<SGN>(O2);
  cpx O1r = cmulf(O1, mkc(C,  SC));
  cpx O3r = cmulf(O3, mkc(-C, SC));
  X[0]=E0+O0;  X[4]=E0-O0;
  X[1]=E1+O1r; X[5]=E1-O1r;
  X[2]=E2+O2r; X[6]=E2-O2r;
  X[3]=E3+O3r; X[7]=E3-O3r;
}

// W16^q = e^{-2pi i q/16}, q=0..7
__device__ __forceinline__ void w16_tab(cpx* W){
  W[0] = mkc( 1.f, 0.f);
  W[1] = mkc( 0.923879533f, -0.382683432f);
  W[2] = mkc( 0.707106781f, -0.707106781f);
  W[3] = mkc( 0.382683432f, -0.923879533f);
  W[4] = mkc( 0.f, -1.f);
  W[5] = mkc(-0.382683432f, -0.923879533f);
  W[6] = mkc(-0.707106781f, -0.707106781f);
  W[7] = mkc(-0.923879533f, -0.382683432f);
}

// first forward stage (t=1024): global reads at u+q*1024 (q<4; upper half is
// the zero padding), LDS writes at SW(u)+q*1024 — single base + immediates.
template<int T>
__device__ void dif8_first_g(cpx* S, const cpx* __restrict__ xb, int tid){
  const float ang = -6.283185307179586f / 8192.f;
  for (int u = tid; u < 1024; u += T){
    cpx* p = S + SW(u);
    cpx a[8], X[8];
#pragma unroll
    for (int q = 0; q < 4; q++) a[q] = xb[u + q*1024];
#pragma unroll
    for (int q = 4; q < 8; q++) a[q] = mkc(0.f, 0.f);
    dft8<-1>(a, X);
    float sn, cn; __sincosf(ang * (float)u, &sn, &cn);
    cpx w = mkc(cn, sn), wq = w;
#pragma unroll
    for (int q = 1; q < 8; q++){ X[q] = cmulf(X[q], wq); wq = cmulf(wq, w); }
#pragma unroll
    for (int q = 0; q < 8; q++) p[q*1024] = X[q];
  }
}

// size-1024 fwd stage (t=128): 2 bases (q parity), immediate offsets.
template<int T>
__device__ void dif8_s1024(cpx* S, int tid){
  const float ang = -6.283185307179586f / 1024.f;
  for (int u = tid; u < 1024; u += T){
    int j = u & 127;
    int base = ((u - j) << 3) + j;
    cpx* pe = S + (base ^ ((j >> 4) & 7));
    cpx* po = S + ((base ^ ((j >> 4) & 7)) ^ 8);
    cpx a[8], X[8];
    a[0]=pe[0];   a[1]=po[128]; a[2]=pe[256]; a[3]=po[384];
    a[4]=pe[512]; a[5]=po[640]; a[6]=pe[768]; a[7]=po[896];
    dft8<-1>(a, X);
    float sn, cn; __sincosf(ang * (float)j, &sn, &cn);
    cpx w = mkc(cn, sn), wq = w;
#pragma unroll
    for (int q = 1; q < 8; q++){ X[q] = cmulf(X[q], wq); wq = cmulf(wq, w); }
    pe[0]=X[0];   po[128]=X[1]; pe[256]=X[2]; po[384]=X[3];
    pe[512]=X[4]; po[640]=X[5]; pe[768]=X[6]; po[896]=X[7];
  }
}

// size-128 fwd stage (t=16): 8 addrs at 2 ops each, computed once & reused.
template<int T>
__device__ void dif8_s128(cpx* S, int tid){
  const float ang = -6.283185307179586f / 128.f;
  for (int u = tid; u < 1024; u += T){
    int j = u & 15;
    int base = ((u - j) << 3) + j;
    int B  = base & ~15;
    int jj = (base & 15) ^ ((base >> 4) & 8);
    int ad[8];
#pragma unroll
    for (int q = 0; q < 8; q++) ad[q] = B + (q << 4) + (jj ^ q);
    cpx a[8], X[8];
#pragma unroll
    for (int q = 0; q < 8; q++) a[q] = S[ad[q]];
    dft8<-1>(a, X);
    float sn, cn; __sincosf(ang * (float)j, &sn, &cn);
    cpx w = mkc(cn, sn), wq = w;
#pragma unroll
    for (int q = 1; q < 8; q++){ X[q] = cmulf(X[q], wq); wq = cmulf(wq, w); }
#pragma unroll
    for (int q = 0; q < 8; q++) S[ad[q]] = X[q];
  }
}

// size-128 inv stage (t=16)
template<int T>
__device__ void dit8_s128(cpx* S, int tid){
  const float ang = 6.283185307179586f / 128.f;
  for (int u = tid; u < 1024; u += T){
    int j = u & 15;
    int base = ((u - j) << 3) + j;
    int B  = base & ~15;
    int jj = (base & 15) ^ ((base >> 4) & 8);
    int ad[8];
#pragma unroll
    for (int q = 0; q < 8; q++) ad[q] = B + (q << 4) + (jj ^ q);
    cpx a[8], X[8];
#pragma unroll
    for (int q = 0; q < 8; q++) a[q] = S[ad[q]];
    float sn, cn; __sincosf(ang * (float)j, &sn, &cn);
    cpx w = mkc(cn, sn), wq = w;
#pragma unroll
    for (int q = 1; q < 8; q++){ a[q] = cmulf(a[q], wq); wq = cmulf(wq, w); }
    dft8<1>(a, X);
#pragma unroll
    for (int q = 0; q < 8; q++) S[ad[q]] = X[q];
  }
}

// size-1024 inv stage (t=128)
template<int T>
__device__ void dit8_s1024(cpx* S, int tid){
  const float ang = 6.283185307179586f / 1024.f;
  for (int u = tid; u < 1024; u += T){
    int j = u & 127;
    int base = ((u - j) << 3) + j;
    cpx* pe = S + (base ^ ((j >> 4) & 7));
    cpx* po = S + ((base ^ ((j >> 4) & 7)) ^ 8);
    cpx a[8], X[8];
    a[0]=pe[0];   a[1]=po[128]; a[2]=pe[256]; a[3]=po[384];
    a[4]=pe[512]; a[5]=po[640]; a[6]=pe[768]; a[7]=po[896];
    float sn, cn; __sincosf(ang * (float)j, &sn, &cn);
    cpx w = mkc(cn, sn), wq = w;
#pragma unroll
    for (int q = 1; q < 8; q++){ a[q] = cmulf(a[q], wq); wq = cmulf(wq, w); }
    dft8<1>(a, X);
    pe[0]=X[0];   po[128]=X[1]; pe[256]=X[2]; po[384]=X[3];
    pe[512]=X[4]; po[640]=X[5]; pe[768]=X[6]; po[896]=X[7];
  }
}

// last inverse stage (t=1024): LDS reads at SW(u)+q*1024 (1 base, immediates),
// only q<4 outputs written DIRECTLY to global (coalesced).
template<int T>
__device__ void dit8_last_g(cpx* S, cpx* __restrict__ yb, int tid){
  const float ang = 6.283185307179586f / 8192.f;
  for (int u = tid; u < 1024; u += T){
    cpx* p = S + SW(u);
    cpx a[8], X[8];
#pragma unroll
    for (int q = 0; q < 8; q++) a[q] = p[q*1024];
    float sn, cn; __sincosf(ang * (float)u, &sn, &cn);
    cpx w = mkc(cn, sn), wq = w;
#pragma unroll
    for (int q = 1; q < 8; q++){ a[q] = cmulf(a[q], wq); wq = cmulf(wq, w); }
    dft8<1>(a, X);
#pragma unroll
    for (int q = 0; q < 4; q++) yb[u + q*1024] = X[q];
  }
}

// merged dif8(size=16) + r2, PAIR-SPLIT (v3-verified pattern): thread pair
// (2v,2v+1) owns block [16v,16v+16); even thread does even offsets (j=0),
// odd does odd offsets (j=1, const W16 twiddles); r2 via shfl_xor(1).
// fma with +-1.0 is exact -> bit-identical to the single-thread version.
template<int T>
__device__ void fwd_tail16_pair(cpx* S, int tid){
  cpx W[8]; w16_tab(W);
  const int half = tid & 1;
  const float sg = half ? -1.f : 1.f;
  for (int v = tid >> 1; v < 512; v += (T >> 1)){
    const int base = v << 4;
    const int sw = v & 15;
    int ad[8];
#pragma unroll
    for (int q = 0; q < 8; q++) ad[q] = (base + ((2*q) ^ sw)) ^ half;
    cpx a[8], X[8];
#pragma unroll
    for (int q = 0; q < 8; q++) a[q] = S[ad[q]];
    dft8<-1>(a, X);
#pragma unroll
    for (int q = 0; q < 8; q++){
      cpx own = half ? cmulf(X[q], W[q]) : X[q];   // odd lane carries X1*W
      cpx oth;
      oth.x = __shfl_xor(own.x, 1, 64);
      oth.y = __shfl_xor(own.y, 1, 64);
      // even: X0 + X1W ; odd: X0 - X1W  == oth + sg*own
      S[ad[q]] = mkc(fmaf(sg, own.x, oth.x), fmaf(sg, own.y, oth.y));
    }
  }
}

// merged r2 + dit8(size=16), pair-split: r2 sum/diff via shfl_xor; odd half
// applies conj(W16) and runs the j=1 inverse dft8.
template<int T>
__device__ void inv_head16_pair(cpx* S, int tid){
  cpx W[8]; w16_tab(W);
  const int half = tid & 1;
  const float sg = half ? -1.f : 1.f;
  for (int v = tid >> 1; v < 512; v += (T >> 1)){
    const int base = v << 4;
    const int sw = v & 15;
    int ad[8];
#pragma unroll
    for (int q = 0; q < 8; q++) ad[q] = (base + ((2*q) ^ sw)) ^ half;
    cpx p[8], X[8];
#pragma unroll
    for (int q = 0; q < 8; q++){
      cpx own = S[ad[q]];
      cpx oth;
      oth.x = __shfl_xor(own.x, 1, 64);
      oth.y = __shfl_xor(own.y, 1, 64);
      // even lane: e+o ; odd lane: e-o  == oth + sg*own
      cpx t1 = mkc(fmaf(sg, own.x, oth.x), fmaf(sg, own.y, oth.y));
      p[q] = half ? cmulcf(t1, W[q]) : t1;   // odd: (e-o)*conj(W16^q)
    }
    dft8<1>(p, X);
#pragma unroll
    for (int q = 0; q < 8; q++) S[ad[q]] = X[q];
  }
}

// sigma for radices (8,8,8,8,2) — v4's verified version
__device__ __forceinline__ int sig8192(int k){
  return ((k & 7) << 10) | (((k >> 3) & 7) << 7) | (((k >> 6) & 7) << 4)
       | (((k >> 9) & 7) << 1) | ((k >> 12) & 1);
}
__device__ __forceinline__ int siginv_even(int m){  // k such that sig8192(k) == 2m
  return (m >> 9) | (((m >> 6) & 7) << 3) | (((m >> 3) & 7) << 6) | ((m & 7) << 9);
}

__device__ __forceinline__ double wsum64(double v){
#pragma unroll
  for (int m = 32; m > 0; m >>= 1) v += __shfl_xor(v, m, 64);
  return v;
}

// A) wave-per-l Cauchy (fp64) -> Hermitian-forced Y[0..8191]; T via WGs>=1025
#define KHAT_CAUCHY_WGS 1025
__global__ __launch_bounds__(256) void s4_khat_kernel(const float* __restrict__ Bp,
                                                      const float* __restrict__ Cp,
                                                      double2* __restrict__ Y,
                                                      double* __restrict__ T){
  const double PI = 3.14159265358979323846264338327950288;
  const int bid = blockIdx.x;
  const int tid = threadIdx.x;
  if (bid >= KHAT_CAUCHY_WGS){
    int d = (bid - KHAT_CAUCHY_WGS) * 256 + tid;
    double phi = PI * (double)(2*d - 1) / 16384.0;
    double s, c; sincos(phi, &s, &c);
    T[d] = c / s;
    return;
  }
  const int l = bid * 4 + (tid >> 6);     // one wave per bin l
  const int n = tid & 63;                 // lane owns pole n
  if (l > 4096) return;
  double th = (2.0 * PI / 8192.0) * (double)l;
  double wr = cos(th), wi = sin(th);
  double ux = 1.0 + wr, uy = wi;
  double vx = 1.0 - wr, vy = -wi;
  double gx = 20.0 * vx, gy = 20.0 * vy;
  double Bn = (double)Bp[n], Cn = (double)Cp[n];
  double Pn = sqrt((double)n + 0.5);
  double lx = -0.5, ly = PI * (double)n;
  double dx = gx - (ux*lx - uy*ly);
  double dy = gy - (ux*ly + uy*lx);
  double inv2 = 2.0 / (dx*dx + dy*dy);
  double cix = dx * inv2, ciy = -dy * inv2;
  double w00 = Cn*Bn, w01 = Cn*Pn, w10 = Pn*Bn, w11 = Pn*Pn;
  double s00x = wsum64(w00*cix), s00y = wsum64(w00*ciy);
  double s01x = wsum64(w01*cix), s01y = wsum64(w01*ciy);
  double s10x = wsum64(w10*cix), s10y = wsum64(w10*ciy);
  double s11x = wsum64(w11*cix), s11y = wsum64(w11*ciy);
  double hux = 0.5*ux, huy = 0.5*uy;
  double k11x = hux*s11x - huy*s11y;
  double k11y = hux*s11y + huy*s11x;
  double p1x = 1.0 + k11x, p1y = k11y;
  double t1x = s01x*p1x - s01y*p1y, t1y = s01x*p1y + s01y*p1x;
  double t2x = t1x*s10x - t1y*s10y, t2y = t1x*s10y + t1y*s10x;
  double crx = t2x*hux - t2y*huy,   cry = t2x*huy + t2y*hux;
  double vr = s00x - crx, vi = s00y - cry;
  if (n == 0){
    if (l == 0 || l == 4096) Y[l] = make_double2(vr, 0.0);
    else                     Y[l] = make_double2(vr, vi);
  } else if (n == 1 && l != 0 && l != 4096){
    Y[8192 - l] = make_double2(vr, -vi);
  }
}

// B) LDS-staged Dirichlet odd bins + S_K + table writes — v4 form, verified
__global__ __launch_bounds__(256) void s4_tabs_kernel(const double2* __restrict__ Y,
                                                      const double* __restrict__ T,
                                                      float2* __restrict__ Ta,
                                                      float2* __restrict__ Tb){
  __shared__ __align__(16) float2 Ys[8192];
  const int tid = threadIdx.x;
  const int g   = blockIdx.x;        // 0..511
  const int lA  = g * 4;
  const int lB  = 4092 - lA;
  double skr = 0.0, ski = 0.0;
  for (int m = tid; m < 8192; m += 256){
    double2 v = Y[m];
    skr += v.x; ski += v.y;
    Ys[m] = make_float2((float)v.x, (float)v.y);
  }
  __syncthreads();
  double aAr[4]={0,0,0,0}, aAi[4]={0,0,0,0};
  double aBr[4]={0,0,0,0}, aBi[4]={0,0,0,0};
#pragma unroll 4
  for (int s = 0; s < 32; s++){
    const int d = (s << 8) + tid;
    const double t = T[d];
#pragma unroll
    for (int j = 0; j < 4; j++){
      float2 va = Ys[(lA + j + d) & 8191];
      float2 vb = Ys[(lB + j + d) & 8191];
      aAr[j] += t * (double)va.x;  aAi[j] += t * (double)va.y;
      aBr[j] += t * (double)vb.x;  aBi[j] += t * (double)vb.y;
    }
  }
  __syncthreads();
  double2 (*red)[9] = (double2 (*)[9])(void*)Ys;
#pragma unroll
  for (int j = 0; j < 4; j++){
    red[tid][j]     = make_double2(aAr[j], aAi[j]);
    red[tid][4 + j] = make_double2(aBr[j], aBi[j]);
  }
  red[tid][8] = make_double2(skr, ski);
  __syncthreads();
  for (int h = 128; h > 0; h >>= 1){
    if (tid < h){
#pragma unroll
      for (int j = 0; j < 9; j++){
        red[tid][j].x += red[tid + h][j].x;
        red[tid][j].y += red[tid + h][j].y;
      }
    }
    __syncthreads();
  }
  if (tid < 4){
    const int l = lA + tid;
    const double SKr = red[0][8].x, SKi = red[0][8].y;
    const double Por = red[0][tid].x, Poi = red[0][tid].y;
    const double Pmr = red[0][4 + (3 - tid)].x, Pmi = red[0][4 + (3 - tid)].y;
    const double q = (1.0/8192.0) * (1.0/8192.0);
    int mo = sig8192(2*l + 1) >> 1;
    Ta[mo] = make_float2((float)((SKr - Poi) * q), (float)((SKi + Por) * q));
    Tb[mo] = make_float2((float)((SKr - Pmi) * q), (float)((SKi + Pmr) * q));
    const double sc = 1.0/8192.0;
    int me = sig8192(2*l) >> 1;
    double2 ye = Y[l];
    double2 yo = Y[4096 - l];
    Ta[me] = make_float2((float)(ye.x * sc), (float)(ye.y * sc));
    Tb[me] = make_float2((float)(yo.x * sc), (float)(yo.y * sc));
  }
  if (g == 0 && tid == 4){
    double2 yn = Y[2048];
    float2 v = make_float2((float)(yn.x / 8192.0), (float)(yn.y / 8192.0));
    Ta[4096] = v; Tb[4096] = v;
  }
}

// C) conv v10 — v9 math, TPB=1024 (8 waves/SIMD), pair-split tails.
__global__ __launch_bounds__(TPB, 8) void s4_conv_kernel(const cpx* __restrict__ x2,
                                                         const cpx* __restrict__ Ta,
                                                         const cpx* __restrict__ Tb,
                                                         cpx* __restrict__ y2){
  __shared__ __align__(16) cpx S[8192];
  const int tid = threadIdx.x;
  const int b = blockIdx.x;
  const cpx* xb = x2 + (size_t)b * 4096;
  dif8_first_g<TPB>(S, xb, tid);   __syncthreads();
  dif8_s1024<TPB>(S, tid);         __syncthreads();
  dif8_s128<TPB>(S, tid);          __syncthreads();
  fwd_tail16_pair<TPB>(S, tid);    __syncthreads();
  for (int m = tid; m < 4097; m += TPB){
    int s, k;
    if (m == 4096){ s = 1; k = 4096; }
    else          { s = 2*m; k = siginv_even(m); }
    int j = (8192 - k) & 8191;
    int sj = sig8192(j);
    int as = SW(s), aj = SW(sj);
    cpx Zk = S[as], Zj = S[aj];
    cpx cZj = mkc(Zj.x, -Zj.y);
    cpx A  = 0.5f * (Zk + cZj);
    cpx Bc = 0.5f * (Zk - cZj);
    float sn, cn; __sincosf(-3.834951969714103e-4f * (float)k, &sn, &cn);
    cpx tb = cmulf(mkc(cn, sn), Bc);
    // tcb == conj(tb) exactly (same partial products) — folded.
    cpx Xk = mkc(A.x + tb.y,  A.y - tb.x);
    cpx Xm = mkc(A.x - tb.y, -A.y - tb.x);
    cpx Yk = cmulf(Xk, Ta[m]);
    cpx Ym = cmulf(Xm, Tb[m]);
    cpx cYm = mkc(Ym.x, -Ym.y);
    cpx E = 0.5f * (Yk + cYm);
    cpx D = 0.5f * (Yk - cYm);
    cpx Od = cmulf(mkc(cn, -sn), D);
    S[as] = mkc(E.x - Od.y, E.y + Od.x);
    if (aj != as)
      S[aj] = mkc(E.x + Od.y, Od.x - E.y);
  }
  __syncthreads();
  inv_head16_pair<TPB>(S, tid);    __syncthreads();
  dit8_s128<TPB>(S, tid);          __syncthreads();
  dit8_s1024<TPB>(S, tid);         __syncthreads();
  cpx* yb = y2 + (size_t)b * 4096;
  dit8_last_g<TPB>(S, yb, tid);
}

extern "C" void kernel_launch(void* const* d_in, const int* in_sizes, int n_in,
                              void* d_out, int out_size, void* d_ws, size_t ws_size,
                              hipStream_t stream){
  (void)n_in; (void)out_size; (void)ws_size;
  const float* x  = (const float*)d_in[0];
  const float* Bp = (const float*)d_in[1];
  const float* Cp = (const float*)d_in[2];
  // ws: Y[8192] double2 @0 (128K), T[8192] double @131072 (64K),
  //     Ta[4097] float2 @196608, Tb[4097] float2 @229632  (~257 KB)
  double2* Yt = (double2*)d_ws;
  double*  Tt = (double*)((char*)d_ws + 131072);
  float2*  Ta = (float2*)((char*)d_ws + 196608);
  float2*  Tb = (float2*)((char*)d_ws + 229632);
  const int batch = in_sizes[0] / 8192;
  hipLaunchKernelGGL(s4_khat_kernel, dim3(KHAT_CAUCHY_WGS + 32), dim3(256), 0, stream,
                     Bp, Cp, Yt, Tt);
  hipLaunchKernelGGL(s4_tabs_kernel, dim3(512), dim3(256), 0, stream, Yt, Tt, Ta, Tb);
  hipLaunchKernelGGL(s4_conv_kernel, dim3(batch), dim3(TPB), 0, stream,
                     (const cpx*)x, (const cpx*)Ta, (const cpx*)Tb, (cpx*)d_out);
}

// Round 10
// 144.080 us; speedup vs baseline: 1.0806x; 1.0050x over previous
//
#include <hip/hip_runtime.h>
#include <math.h>

// S4 DPLR kernel + batched causal convolution via custom packed-real FFTs.
//
//  A) s4_khat_kernel : wave-per-l Cauchy sum (byte-identical, verified).
//  B) s4_tabs_kernel : LDS-staged Dirichlet odd bins + S_K + sigma-permuted
//       pair tables (math byte-identical) + 17 writer WGs (v5-verified
//       pattern) precomputing the pointwise's batch-invariant terms:
//         Tw[m]  = e^{-2pi i k(m)/16384}  (fp64 sincos -> fp32)
//         Taj[m] = SW(sig8192((8192-k(m)) & 8191))
//       where k(m) = siginv_even(m) (k(4096)=4096).
//  C) s4_conv_kernel v11 : v9 structure (TPB=512, packed fp32, linear
//       swizzled addresses — best measured conv 47us) with:
//       (1) pointwise uses Tw/Taj tables: removes ~25 VALU/elem of sigma +
//           __sincosf recompute that every WG redundantly redid. Loads are
//           COALESCED m-indexed (v5's failure was a j-indexed 64B gather;
//           this is the sequential case).
//       (2) wtree8: stage twiddles via depth-3 tree (W2=W1^2, W3=W2W1,
//           W4=W2^2, W5=W3W2, W6=W3^2, W7=W4W3) — same 6 cmulf, but
//           independent of dft8 results so they overlap (v7-verified
//           reassociation; tolerance loose).
//       v10 post-mortem: 2x occupancy (33->63%) left VALUBusy pinned ~63%
//       and conv flat — NOT wave starvation; per-phase instruction count is
//       the only reducible term. TPB back to 512 (v9 best).
//       Fallback (ws too small): TW=false path = exact v9 pointwise.
//
// LDS addresses go through SW(x) = x ^ ((x>>4)&15) (verified swizzle), made
// affine per stage: t=1024 -> 1 base + imms; t=128 -> 2 bases (q parity);
// t=16 -> 8 addrs at 2 ops; tail odd addr = even addr ^ 1.

#define TPB 512

typedef float cpx __attribute__((ext_vector_type(2)));

__device__ __forceinline__ cpx mkc(float x, float y){ cpx r; r.x = x; r.y = y; return r; }

__device__ __forceinline__ int SW(int x){ return x ^ ((x >> 4) & 15); }

// complex mul: a*b = a*b.x + (-a.y,a.x)*b.y  (v_pk_mul + v_pk_fma)
__device__ __forceinline__ cpx cmulf(cpx a, cpx b){
  cpx m = mkc(-a.y, a.x);
  return a * b.x + m * b.y;
}
// a * conj(b)
__device__ __forceinline__ cpx cmulcf(cpx a, cpx b){
  cpx m = mkc(a.y, -a.x);
  return a * b.x + m * b.y;
}
template<int SGN>
__device__ __forceinline__ cpx muli(cpx v){
  return (SGN > 0) ? mkc(-v.y, v.x) : mkc(v.y, -v.x);
}

template<int SGN>   // -1: forward DFT8; +1: conj (unscaled inverse)
__device__ __forceinline__ void dft8(const cpx* a, cpx* X){
  const float C  = 0.70710678118654752f;
  const float SC = (SGN > 0) ? C : -C;
  cpx e0=a[0]+a[4], e1=a[0]-a[4];
  cpx e2=a[2]+a[6], e3=a[2]-a[6];
  cpx f0=a[1]+a[5], f1=a[1]-a[5];
  cpx f2=a[3]+a[7], f3=a[3]-a[7];
  cpx ie3 = muli<SGN>(e3), if3 = muli<SGN>(f3);
  cpx E0=e0+e2, E2=e0-e2;
  cpx E1=e1+ie3, E3=e1-ie3;
  cpx O0=f0+f2, O2=f0-f2;
  cpx O1=f1+if3, O3=f1-if3;
  cpx O2r = muli<SGN>(O2);
  cpx O1r = cmulf(O1, mkc(C,  SC));
  cpx O3r = cmulf(O3, mkc(-C, SC));
  X[0]=E0+O0;  X[4]=E0-O0;
  X[1]=E1+O1r; X[5]=E1-O1r;
  X[2]=E2+O2r; X[6]=E2-O2r;
  X[3]=E3+O3r; X[7]=E3-O3r;
}

// W16^q = e^{-2pi i q/16}, q=0..7
__device__ __forceinline__ void w16_tab(cpx* W){
  W[0] = mkc( 1.f, 0.f);
  W[1] = mkc( 0.923879533f, -0.382683432f);
  W[2] = mkc( 0.707106781f, -0.707106781f);
  W[3] = mkc( 0.382683432f, -0.923879533f);
  W[4] = mkc( 0.f, -1.f);
  W[5] = mkc(-0.382683432f, -0.923879533f);
  W[6] = mkc(-0.707106781f, -0.707106781f);
  W[7] = mkc(-0.923879533f, -0.382683432f);
}

// W[q] = e^{i*ang*q}, q=1..7: one sincosf + 6 cmulf, dep depth 3 (was 6).
__device__ __forceinline__ void wtree8(float ang, cpx* W){
  float sn, cn; __sincosf(ang, &sn, &cn);
  W[1] = mkc(cn, sn);
  W[2] = cmulf(W[1], W[1]);
  W[3] = cmulf(W[2], W[1]);
  W[4] = cmulf(W[2], W[2]);
  W[5] = cmulf(W[3], W[2]);
  W[6] = cmulf(W[3], W[3]);
  W[7] = cmulf(W[4], W[3]);
}

// first forward stage (t=1024): global reads at u+q*1024 (q<4; upper half is
// the zero padding), LDS writes at SW(u)+q*1024 — single base + immediates.
template<int T>
__device__ void dif8_first_g(cpx* S, const cpx* __restrict__ xb, int tid){
  const float ang = -6.283185307179586f / 8192.f;
  for (int u = tid; u < 1024; u += T){
    cpx* p = S + SW(u);
    cpx a[8], X[8];
#pragma unroll
    for (int q = 0; q < 4; q++) a[q] = xb[u + q*1024];
#pragma unroll
    for (int q = 4; q < 8; q++) a[q] = mkc(0.f, 0.f);
    cpx W[8]; wtree8(ang * (float)u, W);
    dft8<-1>(a, X);
#pragma unroll
    for (int q = 1; q < 8; q++) X[q] = cmulf(X[q], W[q]);
#pragma unroll
    for (int q = 0; q < 8; q++) p[q*1024] = X[q];
  }
}

// size-1024 fwd stage (t=128): 2 bases (q parity), immediate offsets.
template<int T>
__device__ void dif8_s1024(cpx* S, int tid){
  const float ang = -6.283185307179586f / 1024.f;
  for (int u = tid; u < 1024; u += T){
    int j = u & 127;
    int base = ((u - j) << 3) + j;
    cpx* pe = S + (base ^ ((j >> 4) & 7));
    cpx* po = S + ((base ^ ((j >> 4) & 7)) ^ 8);
    cpx a[8], X[8];
    a[0]=pe[0];   a[1]=po[128]; a[2]=pe[256]; a[3]=po[384];
    a[4]=pe[512]; a[5]=po[640]; a[6]=pe[768]; a[7]=po[896];
    cpx W[8]; wtree8(ang * (float)j, W);
    dft8<-1>(a, X);
#pragma unroll
    for (int q = 1; q < 8; q++) X[q] = cmulf(X[q], W[q]);
    pe[0]=X[0];   po[128]=X[1]; pe[256]=X[2]; po[384]=X[3];
    pe[512]=X[4]; po[640]=X[5]; pe[768]=X[6]; po[896]=X[7];
  }
}

// size-128 fwd stage (t=16): 8 addrs at 2 ops each, computed once & reused.
template<int T>
__device__ void dif8_s128(cpx* S, int tid){
  const float ang = -6.283185307179586f / 128.f;
  for (int u = tid; u < 1024; u += T){
    int j = u & 15;
    int base = ((u - j) << 3) + j;
    int B  = base & ~15;
    int jj = (base & 15) ^ ((base >> 4) & 8);
    int ad[8];
#pragma unroll
    for (int q = 0; q < 8; q++) ad[q] = B + (q << 4) + (jj ^ q);
    cpx a[8], X[8];
#pragma unroll
    for (int q = 0; q < 8; q++) a[q] = S[ad[q]];
    cpx W[8]; wtree8(ang * (float)j, W);
    dft8<-1>(a, X);
#pragma unroll
    for (int q = 1; q < 8; q++) X[q] = cmulf(X[q], W[q]);
#pragma unroll
    for (int q = 0; q < 8; q++) S[ad[q]] = X[q];
  }
}

// size-128 inv stage (t=16)
template<int T>
__device__ void dit8_s128(cpx* S, int tid){
  const float ang = 6.283185307179586f / 128.f;
  for (int u = tid; u < 1024; u += T){
    int j = u & 15;
    int base = ((u - j) << 3) + j;
    int B  = base & ~15;
    int jj = (base & 15) ^ ((base >> 4) & 8);
    int ad[8];
#pragma unroll
    for (int q = 0; q < 8; q++) ad[q] = B + (q << 4) + (jj ^ q);
    cpx a[8], X[8];
#pragma unroll
    for (int q = 0; q < 8; q++) a[q] = S[ad[q]];
    cpx W[8]; wtree8(ang * (float)j, W);
#pragma unroll
    for (int q = 1; q < 8; q++) a[q] = cmulf(a[q], W[q]);
    dft8<1>(a, X);
#pragma unroll
    for (int q = 0; q < 8; q++) S[ad[q]] = X[q];
  }
}

// size-1024 inv stage (t=128)
template<int T>
__device__ void dit8_s1024(cpx* S, int tid){
  const float ang = 6.283185307179586f / 1024.f;
  for (int u = tid; u < 1024; u += T){
    int j = u & 127;
    int base = ((u - j) << 3) + j;
    cpx* pe = S + (base ^ ((j >> 4) & 7));
    cpx* po = S + ((base ^ ((j >> 4) & 7)) ^ 8);
    cpx a[8], X[8];
    a[0]=pe[0];   a[1]=po[128]; a[2]=pe[256]; a[3]=po[384];
    a[4]=pe[512]; a[5]=po[640]; a[6]=pe[768]; a[7]=po[896];
    cpx W[8]; wtree8(ang * (float)j, W);
#pragma unroll
    for (int q = 1; q < 8; q++) a[q] = cmulf(a[q], W[q]);
    dft8<1>(a, X);
    pe[0]=X[0];   po[128]=X[1]; pe[256]=X[2]; po[384]=X[3];
    pe[512]=X[4]; po[640]=X[5]; pe[768]=X[6]; po[896]=X[7];
  }
}

// last inverse stage (t=1024): LDS reads at SW(u)+q*1024 (1 base, immediates),
// only q<4 outputs written DIRECTLY to global (coalesced).
template<int T>
__device__ void dit8_last_g(cpx* S, cpx* __restrict__ yb, int tid){
  const float ang = 6.283185307179586f / 8192.f;
  for (int u = tid; u < 1024; u += T){
    cpx* p = S + SW(u);
    cpx a[8], X[8];
#pragma unroll
    for (int q = 0; q < 8; q++) a[q] = p[q*1024];
    cpx W[8]; wtree8(ang * (float)u, W);
#pragma unroll
    for (int q = 1; q < 8; q++) a[q] = cmulf(a[q], W[q]);
    dft8<1>(a, X);
#pragma unroll
    for (int q = 0; q < 4; q++) yb[u + q*1024] = X[q];
  }
}

// merged dif8(size=16) + r2: thread v owns block [16v,16v+16); odd address =
// even address ^ 1; addresses computed once & reused. (v9-verified)
template<int T>
__device__ void fwd_tail16(cpx* S, int tid){
  cpx W[8]; w16_tab(W);
  for (int v = tid; v < 512; v += T){
    const int base = v << 4;
    const int sw = v & 15;
    int ae[8];
#pragma unroll
    for (int q = 0; q < 8; q++) ae[q] = base + ((2*q) ^ sw);
    cpx a0[8], a1[8], X0[8], X1[8];
#pragma unroll
    for (int q = 0; q < 8; q++){
      a0[q] = S[ae[q]];
      a1[q] = S[ae[q] ^ 1];
    }
    dft8<-1>(a0, X0);
    dft8<-1>(a1, X1);
#pragma unroll
    for (int q = 0; q < 8; q++){
      cpx tq = cmulf(X1[q], W[q]);          // j=1 twiddle (const)
      S[ae[q]]     = X0[q] + tq;            // r2 sum
      S[ae[q] ^ 1] = X0[q] - tq;            // r2 diff
    }
  }
}

// merged r2 + dit8(size=16)  (v9-verified)
template<int T>
__device__ void inv_head16(cpx* S, int tid){
  cpx W[8]; w16_tab(W);
  for (int v = tid; v < 512; v += T){
    const int base = v << 4;
    const int sw = v & 15;
    int ae[8];
#pragma unroll
    for (int q = 0; q < 8; q++) ae[q] = base + ((2*q) ^ sw);
    cpx p0[8], p1[8], X0[8], X1[8];
#pragma unroll
    for (int q = 0; q < 8; q++){
      cpx e = S[ae[q]];
      cpx o = S[ae[q] ^ 1];
      p0[q] = e + o;
      p1[q] = cmulcf(e - o, W[q]);
    }
    dft8<1>(p0, X0);
    dft8<1>(p1, X1);
#pragma unroll
    for (int q = 0; q < 8; q++){
      S[ae[q]]     = X0[q];
      S[ae[q] ^ 1] = X1[q];
    }
  }
}

// sigma for radices (8,8,8,8,2) — verified
__device__ __forceinline__ int sig8192(int k){
  return ((k & 7) << 10) | (((k >> 3) & 7) << 7) | (((k >> 6) & 7) << 4)
       | (((k >> 9) & 7) << 1) | ((k >> 12) & 1);
}
__device__ __forceinline__ int siginv_even(int m){  // k such that sig8192(k) == 2m
  return (m >> 9) | (((m >> 6) & 7) << 3) | (((m >> 3) & 7) << 6) | ((m & 7) << 9);
}

__device__ __forceinline__ double wsum64(double v){
#pragma unroll
  for (int m = 32; m > 0; m >>= 1) v += __shfl_xor(v, m, 64);
  return v;
}

// A) wave-per-l Cauchy (fp64) -> Hermitian-forced Y[0..8191]; T via WGs>=1025
#define KHAT_CAUCHY_WGS 1025
__global__ __launch_bounds__(256) void s4_khat_kernel(const float* __restrict__ Bp,
                                                      const float* __restrict__ Cp,
                                                      double2* __restrict__ Y,
                                                      double* __restrict__ T){
  const double PI = 3.14159265358979323846264338327950288;
  const int bid = blockIdx.x;
  const int tid = threadIdx.x;
  if (bid >= KHAT_CAUCHY_WGS){
    int d = (bid - KHAT_CAUCHY_WGS) * 256 + tid;
    double phi = PI * (double)(2*d - 1) / 16384.0;
    double s, c; sincos(phi, &s, &c);
    T[d] = c / s;
    return;
  }
  const int l = bid * 4 + (tid >> 6);     // one wave per bin l
  const int n = tid & 63;                 // lane owns pole n
  if (l > 4096) return;
  double th = (2.0 * PI / 8192.0) * (double)l;
  double wr = cos(th), wi = sin(th);
  double ux = 1.0 + wr, uy = wi;
  double vx = 1.0 - wr, vy = -wi;
  double gx = 20.0 * vx, gy = 20.0 * vy;
  double Bn = (double)Bp[n], Cn = (double)Cp[n];
  double Pn = sqrt((double)n + 0.5);
  double lx = -0.5, ly = PI * (double)n;
  double dx = gx - (ux*lx - uy*ly);
  double dy = gy - (ux*ly + uy*lx);
  double inv2 = 2.0 / (dx*dx + dy*dy);
  double cix = dx * inv2, ciy = -dy * inv2;
  double w00 = Cn*Bn, w01 = Cn*Pn, w10 = Pn*Bn, w11 = Pn*Pn;
  double s00x = wsum64(w00*cix), s00y = wsum64(w00*ciy);
  double s01x = wsum64(w01*cix), s01y = wsum64(w01*ciy);
  double s10x = wsum64(w10*cix), s10y = wsum64(w10*ciy);
  double s11x = wsum64(w11*cix), s11y = wsum64(w11*ciy);
  double hux = 0.5*ux, huy = 0.5*uy;
  double k11x = hux*s11x - huy*s11y;
  double k11y = hux*s11y + huy*s11x;
  double p1x = 1.0 + k11x, p1y = k11y;
  double t1x = s01x*p1x - s01y*p1y, t1y = s01x*p1y + s01y*p1x;
  double t2x = t1x*s10x - t1y*s10y, t2y = t1x*s10y + t1y*s10x;
  double crx = t2x*hux - t2y*huy,   cry = t2x*huy + t2y*hux;
  double vr = s00x - crx, vi = s00y - cry;
  if (n == 0){
    if (l == 0 || l == 4096) Y[l] = make_double2(vr, 0.0);
    else                     Y[l] = make_double2(vr, vi);
  } else if (n == 1 && l != 0 && l != 4096){
    Y[8192 - l] = make_double2(vr, -vi);
  }
}

// B) tabs (math unchanged, verified) + Tw/Taj writer WGs (g >= 512).
__global__ __launch_bounds__(256) void s4_tabs_kernel(const double2* __restrict__ Y,
                                                      const double* __restrict__ T,
                                                      float2* __restrict__ Ta,
                                                      float2* __restrict__ Tb,
                                                      float2* __restrict__ Tw,
                                                      int*    __restrict__ Taj){
  const int tid = threadIdx.x;
  const int g   = blockIdx.x;        // 0..511 tabs, 512..528 Tw/Taj writers
  if (g >= 512){
    int idx = ((g - 512) << 8) + tid;        // 0..4351
    if (idx <= 4096){
      int k = (idx == 4096) ? 4096 : siginv_even(idx);
      double ang = -6.283185307179586476925286766559 * (double)k / 16384.0;
      double s, c; sincos(ang, &s, &c);
      Tw[idx] = make_float2((float)c, (float)s);
      int j = (8192 - k) & 8191;
      Taj[idx] = SW(sig8192(j));
    }
    return;
  }
  __shared__ __align__(16) float2 Ys[8192];
  const int lA  = g * 4;
  const int lB  = 4092 - lA;
  double skr = 0.0, ski = 0.0;
  for (int m = tid; m < 8192; m += 256){
    double2 v = Y[m];
    skr += v.x; ski += v.y;
    Ys[m] = make_float2((float)v.x, (float)v.y);
  }
  __syncthreads();
  double aAr[4]={0,0,0,0}, aAi[4]={0,0,0,0};
  double aBr[4]={0,0,0,0}, aBi[4]={0,0,0,0};
#pragma unroll 4
  for (int s = 0; s < 32; s++){
    const int d = (s << 8) + tid;
    const double t = T[d];
#pragma unroll
    for (int j = 0; j < 4; j++){
      float2 va = Ys[(lA + j + d) & 8191];
      float2 vb = Ys[(lB + j + d) & 8191];
      aAr[j] += t * (double)va.x;  aAi[j] += t * (double)va.y;
      aBr[j] += t * (double)vb.x;  aBi[j] += t * (double)vb.y;
    }
  }
  __syncthreads();
  double2 (*red)[9] = (double2 (*)[9])(void*)Ys;
#pragma unroll
  for (int j = 0; j < 4; j++){
    red[tid][j]     = make_double2(aAr[j], aAi[j]);
    red[tid][4 + j] = make_double2(aBr[j], aBi[j]);
  }
  red[tid][8] = make_double2(skr, ski);
  __syncthreads();
  for (int h = 128; h > 0; h >>= 1){
    if (tid < h){
#pragma unroll
      for (int j = 0; j < 9; j++){
        red[tid][j].x += red[tid + h][j].x;
        red[tid][j].y += red[tid + h][j].y;
      }
    }
    __syncthreads();
  }
  if (tid < 4){
    const int l = lA + tid;
    const double SKr = red[0][8].x, SKi = red[0][8].y;
    const double Por = red[0][tid].x, Poi = red[0][tid].y;
    const double Pmr = red[0][4 + (3 - tid)].x, Pmi = red[0][4 + (3 - tid)].y;
    const double q = (1.0/8192.0) * (1.0/8192.0);
    int mo = sig8192(2*l + 1) >> 1;
    Ta[mo] = make_float2((float)((SKr - Poi) * q), (float)((SKi + Por) * q));
    Tb[mo] = make_float2((float)((SKr - Pmi) * q), (float)((SKi + Pmr) * q));
    const double sc = 1.0/8192.0;
    int me = sig8192(2*l) >> 1;
    double2 ye = Y[l];
    double2 yo = Y[4096 - l];
    Ta[me] = make_float2((float)(ye.x * sc), (float)(ye.y * sc));
    Tb[me] = make_float2((float)(yo.x * sc), (float)(yo.y * sc));
  }
  if (g == 0 && tid == 4){
    double2 yn = Y[2048];
    float2 v = make_float2((float)(yn.x / 8192.0), (float)(yn.y / 8192.0));
    Ta[4096] = v; Tb[4096] = v;
  }
}

// C) conv v11 — v9 structure + wtree8 + table-driven pointwise (TW).
template<bool TW>
__global__ __launch_bounds__(TPB, 4) void s4_conv_kernel(const cpx* __restrict__ x2,
                                                         const cpx* __restrict__ Ta,
                                                         const cpx* __restrict__ Tb,
                                                         const cpx* __restrict__ Tw,
                                                         const int* __restrict__ Taj,
                                                         cpx* __restrict__ y2){
  __shared__ __align__(16) cpx S[8192];
  const int tid = threadIdx.x;
  const int b = blockIdx.x;
  const cpx* xb = x2 + (size_t)b * 4096;
  dif8_first_g<TPB>(S, xb, tid);  __syncthreads();
  dif8_s1024<TPB>(S, tid);        __syncthreads();
  dif8_s128<TPB>(S, tid);         __syncthreads();
  fwd_tail16<TPB>(S, tid);        __syncthreads();
  for (int m = tid; m < 4097; m += TPB){
    int s = (m == 4096) ? 1 : 2*m;
    int as = SW(s);
    int aj;
    float sn, cn;
    if constexpr (TW){
      aj = Taj[m];
      cpx Wk = Tw[m];
      cn = Wk.x; sn = Wk.y;
    } else {
      int k = (m == 4096) ? 4096 : siginv_even(m);
      int j = (8192 - k) & 8191;
      aj = SW(sig8192(j));
      __sincosf(-3.834951969714103e-4f * (float)k, &sn, &cn);
    }
    cpx Zk = S[as], Zj = S[aj];
    cpx cZj = mkc(Zj.x, -Zj.y);
    cpx A  = 0.5f * (Zk + cZj);
    cpx Bc = 0.5f * (Zk - cZj);
    cpx tb = cmulf(mkc(cn, sn), Bc);
    // tcb == conj(tb) exactly (same partial products) — folded.
    cpx Xk = mkc(A.x + tb.y,  A.y - tb.x);
    cpx Xm = mkc(A.x - tb.y, -A.y - tb.x);
    cpx Yk = cmulf(Xk, Ta[m]);
    cpx Ym = cmulf(Xm, Tb[m]);
    cpx cYm = mkc(Ym.x, -Ym.y);
    cpx E = 0.5f * (Yk + cYm);
    cpx D = 0.5f * (Yk - cYm);
    cpx Od = cmulf(mkc(cn, -sn), D);
    S[as] = mkc(E.x - Od.y, E.y + Od.x);
    if (aj != as)
      S[aj] = mkc(E.x + Od.y, Od.x - E.y);
  }
  __syncthreads();
  inv_head16<TPB>(S, tid);        __syncthreads();
  dit8_s128<TPB>(S, tid);         __syncthreads();
  dit8_s1024<TPB>(S, tid);        __syncthreads();
  cpx* yb = y2 + (size_t)b * 4096;
  dit8_last_g<TPB>(S, yb, tid);
}

extern "C" void kernel_launch(void* const* d_in, const int* in_sizes, int n_in,
                              void* d_out, int out_size, void* d_ws, size_t ws_size,
                              hipStream_t stream){
  (void)n_in; (void)out_size;
  const float* x  = (const float*)d_in[0];
  const float* Bp = (const float*)d_in[1];
  const float* Cp = (const float*)d_in[2];
  // ws: Y[8192] double2 @0 (128K), T[8192] double @131072 (64K),
  //     Ta[4097] float2 @196608, Tb[4097] float2 @229632,
  //     Tw[4097] float2 @262912, Taj[4097] int @295936  => ends ~312324
  double2* Yt = (double2*)d_ws;
  double*  Tt = (double*)((char*)d_ws + 131072);
  float2*  Ta = (float2*)((char*)d_ws + 196608);
  float2*  Tb = (float2*)((char*)d_ws + 229632);
  float2*  Tw = (float2*)((char*)d_ws + 262912);
  int*     Taj= (int*)   ((char*)d_ws + 295936);
  const bool use_tab = ws_size >= (size_t)312330;
  const int batch = in_sizes[0] / 8192;
  hipLaunchKernelGGL(s4_khat_kernel, dim3(KHAT_CAUCHY_WGS + 32), dim3(256), 0, stream,
                     Bp, Cp, Yt, Tt);
  hipLaunchKernelGGL(s4_tabs_kernel, dim3(use_tab ? 529 : 512), dim3(256), 0, stream,
                     Yt, Tt, Ta, Tb, Tw, Taj);
  if (use_tab)
    hipLaunchKernelGGL(s4_conv_kernel<true>, dim3(batch), dim3(TPB), 0, stream,
                       (const cpx*)x, (const cpx*)Ta, (const cpx*)Tb,
                       (const cpx*)Tw, Taj, (cpx*)d_out);
  else
    hipLaunchKernelGGL(s4_conv_kernel<false>, dim3(batch), dim3(TPB), 0, stream,
                       (const cpx*)x, (const cpx*)Ta, (const cpx*)Tb,
                       (const cpx*)Tw, Taj, (cpx*)d_out);
}